// Round 3
// baseline (1575.043 us; speedup 1.0000x reference)
//
#include <hip/hip_runtime.h>
#include <hip/hip_bf16.h>

#define NN 100000
#define NE 1600000
#define SCAN_T 256
#define SCAN_E 1024
#define SCAN_NB ((NN + SCAN_E - 1) / SCAN_E)   // 98

static __device__ __forceinline__ float bf2f(__hip_bfloat16 v) { return __bfloat162float(v); }

// ---------------- fp8 e4m3 (OCP) encode/decode, hand-rolled ----------------
// decode: any byte -> finite float (e=15,m=7 decodes to 480, never NaN)
static __device__ __forceinline__ float f8d(unsigned char b) {
    unsigned e = (b >> 3) & 15u, m = b & 7u;
    float mag;
    if (e == 0) mag = (float)m * 0.001953125f;                       // m * 2^-9
    else        mag = __uint_as_float(((e + 120u) << 23) | (m << 20));
    return (b & 0x80u) ? -mag : mag;
}
// encode: round-to-nearest-ish, saturate to +-448, NaN/Inf -> +-448, tiny -> 0
static __device__ __forceinline__ unsigned char f8e(float x) {
    unsigned u = __float_as_uint(x);
    unsigned s = (u >> 31) << 7;
    unsigned au = u & 0x7fffffffu;
    if (au >= 0x43E00000u) return (unsigned char)(s | 0x7Eu);        // >= 448 (or inf/nan)
    if (au <  0x3A800000u) return (unsigned char)s;                  // < 2^-10 -> 0
    if (au <  0x3C800000u) {                                         // subnormal: < 2^-6
        float a = __uint_as_float(au);
        int m = (int)rintf(a * 512.0f);                              // multiples of 2^-9
        if (m >= 8) return (unsigned char)(s | 0x08u);               // rounds up to 2^-6
        return (unsigned char)(s | (unsigned)m);
    }
    au += 0x80000u;                                                  // round at bit 20
    if (au >= 0x43E00000u) return (unsigned char)(s | 0x7Eu);
    unsigned e = (au >> 23) - 120u;
    unsigned m = (au >> 20) & 7u;
    return (unsigned char)(s | (e << 3) | m);
}

// ---------------- dtype probes: flags[0]=x_is_f32, flags[1]=edge_is_i64 -------
__global__ void k_probe(const unsigned short* __restrict__ xw,
                        const int* __restrict__ ei, int* __restrict__ flags) {
    __shared__ int cnt_nan, odd_nz;
    if (threadIdx.x == 0) { cnt_nan = 0; odd_nz = 0; }
    __syncthreads();
    for (int i = threadIdx.x; i < 65536; i += 256) {
        unsigned short w = xw[i];
        if ((w & 0x7F80u) == 0x7F80u) atomicAdd(&cnt_nan, 1);   // bf16 inf/nan pattern
    }
    if (threadIdx.x < 256) {
        if (ei[2 * threadIdx.x + 1] != 0) atomicAdd(&odd_nz, 1);
    }
    __syncthreads();
    if (threadIdx.x == 0) {
        flags[0] = (cnt_nan > 0) ? 1 : 0;   // true f32 data misread as bf16 shows nan patterns
        flags[1] = (odd_nz == 0) ? 1 : 0;   // int64: high words all zero
    }
}

static __device__ __forceinline__ int e_src(const int* ei, int e, int f64) {
    int v = f64 ? ei[2 * e] : ei[e];
    return min(max(v, 0), NN - 1);
}
static __device__ __forceinline__ int e_dst(const int* ei, int e, int f64) {
    int v = f64 ? ei[2 * (NE + e)] : ei[NE + e];
    return min(max(v, 0), NN - 1);
}
static __device__ __forceinline__ float ldx(const void* p, long long i, int f32) {
    return f32 ? ((const float*)p)[i] : bf2f(((const __hip_bfloat16*)p)[i]);
}

// ---------------- parameter conversion -> f32 ----------------
__global__ void cvt_params(const void* W1, const void* b1, const void* W2, const void* b2,
                           const void* W3, const void* b3, const void* Wa,
                           float* W1f, float* b1f, float* W2f, float* b2f,
                           float* W3f, float* b3f, float* Waf, const int* flags) {
    int i = blockIdx.x * blockDim.x + threadIdx.x;
    int f = flags[0];
    if (i < 16384) { W1f[i] = ldx(W1, i, f); W2f[i] = ldx(W2, i, f); }
    if (i < 8192)  W3f[i] = ldx(W3, i, f);
    if (i < 4096)  Waf[i] = ldx(Wa, i, f);
    if (i < 128)   { b1f[i] = ldx(b1, i, f); b2f[i] = ldx(b2, i, f); }
    if (i < 64)    b3f[i] = ldx(b3, i, f);
}

// ---------------- degree count + dis ----------------
__global__ void k_count(const int* __restrict__ ei, int* __restrict__ counts,
                        const int* __restrict__ flags) {
    int e = blockIdx.x * blockDim.x + threadIdx.x;
    if (e < NE) atomicAdd(&counts[e_dst(ei, e, flags[1])], 1);
}

__global__ void k_dis(const int* __restrict__ counts, float* __restrict__ dis) {
    int n = blockIdx.x * blockDim.x + threadIdx.x;
    if (n < NN) dis[n] = rsqrtf((float)counts[n] + 1.0f);
}

// ---------------- exclusive scan over counts -> rowptr ----------------
__global__ void k_scan1(const int* __restrict__ counts, int* __restrict__ bsum) {
    __shared__ int sd[SCAN_T];
    int b = blockIdx.x, t = threadIdx.x;
    int base = b * SCAN_E + t * 4;
    int s = 0;
#pragma unroll
    for (int i = 0; i < 4; i++) { int idx = base + i; if (idx < NN) s += counts[idx]; }
    sd[t] = s; __syncthreads();
    for (int o = SCAN_T / 2; o > 0; o >>= 1) {
        if (t < o) sd[t] += sd[t + o];
        __syncthreads();
    }
    if (t == 0) bsum[b] = sd[0];
}

__global__ void k_scan2(const int* __restrict__ bsum, int* __restrict__ boff,
                        int* __restrict__ rowptr) {
    if (threadIdx.x == 0 && blockIdx.x == 0) {
        int run = 0;
        for (int b = 0; b < SCAN_NB; b++) { boff[b] = run; run += bsum[b]; }
        rowptr[NN] = run;
    }
}

__global__ void k_scan3(const int* __restrict__ counts, const int* __restrict__ boff,
                        int* __restrict__ rowptr) {
    __shared__ int sd[SCAN_T];
    int b = blockIdx.x, t = threadIdx.x;
    int base = b * SCAN_E + t * 4;
    int v[4]; int s = 0;
#pragma unroll
    for (int i = 0; i < 4; i++) { int idx = base + i; v[i] = (idx < NN) ? counts[idx] : 0; s += v[i]; }
    sd[t] = s; __syncthreads();
    for (int o = 1; o < SCAN_T; o <<= 1) {
        int add = (t >= o) ? sd[t - o] : 0;
        __syncthreads();
        sd[t] += add;
        __syncthreads();
    }
    int run = sd[t] - s + boff[b];
#pragma unroll
    for (int i = 0; i < 4; i++) {
        int idx = base + i;
        if (idx < NN) { rowptr[idx] = run; run += v[i]; }
    }
}

__global__ void k_place(const int* __restrict__ ei, const int* __restrict__ rowptr,
                        int* __restrict__ cursor, int* __restrict__ csr_src,
                        const int* __restrict__ flags) {
    int e = blockIdx.x * blockDim.x + threadIdx.x;
    if (e < NE) {
        int f64 = flags[1];
        int d = e_dst(ei, e, f64);
        int p = rowptr[d] + atomicAdd(&cursor[d], 1);
        p = min(max(p, 0), NE - 1);
        csr_src[p] = e_src(ei, e, f64);
    }
}

// ---------------- L1 aggregation: G = Anorm @ x  (x bf16 or f32 -> fp8) -------
__global__ void k_aggx(const void* __restrict__ x, const int* __restrict__ rowptr,
                       const int* __restrict__ csr_src, const float* __restrict__ dis,
                       unsigned char* __restrict__ G, const int* __restrict__ flags) {
    int n = blockIdx.x;
    int f = threadIdx.x;          // 128
    int xf = flags[0];
    float dn = dis[n];
    int s0 = rowptr[n], s1 = rowptr[n + 1];
    s0 = min(max(s0, 0), NE); s1 = min(max(s1, s0), NE);
    float acc = ldx(x, (long long)n * 128 + f, xf) * dn * dn;
    if (xf) {
        const float* xp = (const float*)x;
        for (int j = s0; j < s1; j++) {
            int s = min(max(csr_src[j], 0), NN - 1);
            acc += xp[(long long)s * 128 + f] * (dis[s] * dn);
        }
    } else {
        const __hip_bfloat16* xp = (const __hip_bfloat16*)x;
        for (int j = s0; j < s1; j++) {
            int s = min(max(csr_src[j], 0), NN - 1);
            acc += bf2f(xp[(long long)s * 128 + f]) * (dis[s] * dn);
        }
    }
    G[(long long)n * 128 + f] = f8e(acc);
}

// ---------------- aggregation on fp8 table: G = Anorm @ H ----------------
__global__ void k_agg8(const unsigned char* __restrict__ H, const int* __restrict__ rowptr,
                       const int* __restrict__ csr_src, const float* __restrict__ dis,
                       unsigned char* __restrict__ G) {
    int n = blockIdx.x;
    int f = threadIdx.x;          // 128
    float dn = dis[n];
    int s0 = rowptr[n], s1 = rowptr[n + 1];
    s0 = min(max(s0, 0), NE); s1 = min(max(s1, s0), NE);
    float acc = f8d(H[(long long)n * 128 + f]) * dn * dn;
    for (int j = s0; j < s1; j++) {
        int s = min(max(csr_src[j], 0), NN - 1);
        acc += f8d(H[(long long)s * 128 + f]) * (dis[s] * dn);
    }
    G[(long long)n * 128 + f] = f8e(acc);
}

// ---------------- row-local transform: H = relu(G @ W + b), fp8 -> fp8 --------
// 8 rows per block, 128 threads (one output column each)
__global__ void k_xform(const unsigned char* __restrict__ G, const float* __restrict__ W,
                        const float* __restrict__ b, unsigned char* __restrict__ H) {
    __shared__ float rows[8][128];
    int n0 = blockIdx.x * 8;
    int f = threadIdx.x;
    for (int idx = f; idx < 8 * 128; idx += 128) {
        int r = idx >> 7, k = idx & 127;
        int n = n0 + r;
        rows[r][k] = (n < NN) ? f8d(G[(long long)n * 128 + k]) : 0.0f;
    }
    __syncthreads();
    float bias = b[f];
    for (int r = 0; r < 8; r++) {
        int n = n0 + r;
        if (n >= NN) break;
        float acc = bias;
#pragma unroll 8
        for (int k = 0; k < 128; k++) acc += rows[r][k] * W[k * 128 + f];
        acc = fmaxf(acc, 0.0f);
        H[(long long)n * 128 + f] = f8e(acc);
    }
}

// ---------------- final transform: h3 = G @ W3 + b3, fp8 -> bf16 (into Hb) ----
__global__ void k_xform3(const unsigned char* __restrict__ G, const float* __restrict__ W,
                         const float* __restrict__ b, __hip_bfloat16* __restrict__ Hb) {
    __shared__ float rows[8][128];
    int n0 = blockIdx.x * 8;
    int f = threadIdx.x;          // 64
    for (int idx = f; idx < 8 * 128; idx += 64) {
        int r = idx >> 7, k = idx & 127;
        int n = n0 + r;
        rows[r][k] = (n < NN) ? f8d(G[(long long)n * 128 + k]) : 0.0f;
    }
    __syncthreads();
    float bias = b[f];
    for (int r = 0; r < 8; r++) {
        int n = n0 + r;
        if (n >= NN) break;
        float acc = bias;
#pragma unroll 8
        for (int k = 0; k < 128; k++) acc += rows[r][k] * W[k * 64 + f];
        Hb[(long long)n * 64 + f] = __float2bfloat16(acc);
    }
}

// ---------------- attention pooling on Hb (bf16 h3 in ws) ----------------
__global__ void k_colsum(const __hip_bfloat16* __restrict__ h3, float* __restrict__ colsum) {
    int lane = threadIdx.x & 63;
    int wave = (blockIdx.x * blockDim.x + threadIdx.x) >> 6;
    int nw = (gridDim.x * blockDim.x) >> 6;
    float acc = 0.0f;
    for (int n = wave; n < NN; n += nw) acc += bf2f(h3[(long long)n * 64 + lane]);
    __shared__ float sd[256];
    sd[threadIdx.x] = acc; __syncthreads();
    if (threadIdx.x < 64)
        atomicAdd(&colsum[threadIdx.x],
                  sd[threadIdx.x] + sd[threadIdx.x + 64] + sd[threadIdx.x + 128] + sd[threadIdx.x + 192]);
}

__global__ void k_ctx(const float* __restrict__ colsum, const float* __restrict__ Wa,
                      float* __restrict__ ctx) {
    __shared__ float ms[64];
    int j = threadIdx.x;
    ms[j] = colsum[j] * (1.0f / NN);
    __syncthreads();
    float s = 0.0f;
#pragma unroll
    for (int k = 0; k < 64; k++) s += ms[k] * Wa[k * 64 + j];
    ctx[j] = tanhf(s);
}

__global__ void k_pool(const __hip_bfloat16* __restrict__ h3, const float* __restrict__ ctx,
                       float* __restrict__ pooled) {
    int lane = threadIdx.x & 63;
    int wave = (blockIdx.x * blockDim.x + threadIdx.x) >> 6;
    int nw = (gridDim.x * blockDim.x) >> 6;
    float c = ctx[lane];
    float acc = 0.0f;
    for (int n = wave; n < NN; n += nw) {
        float v = bf2f(h3[(long long)n * 64 + lane]);
        float p = v * c;
#pragma unroll
        for (int m = 32; m > 0; m >>= 1) p += __shfl_xor(p, m, 64);
        float score = 1.0f / (1.0f + expf(-p));
        acc += score * v;
    }
    __shared__ float sd[256];
    sd[threadIdx.x] = acc; __syncthreads();
    if (threadIdx.x < 64)
        atomicAdd(&pooled[threadIdx.x],
                  sd[threadIdx.x] + sd[threadIdx.x + 64] + sd[threadIdx.x + 128] + sd[threadIdx.x + 192]);
}

// ---------------- final output write (bf16 or f32 d_out per flag) -------------
__global__ void k_out(const __hip_bfloat16* __restrict__ h3, const float* __restrict__ pooled,
                      void* __restrict__ out, const int* __restrict__ flags) {
    long long i = (long long)blockIdx.x * blockDim.x + threadIdx.x;
    if (i >= 6400064LL) return;
    float v = (i < 6400000LL) ? bf2f(h3[i]) : pooled[i - 6400000LL];
    if (flags[0]) ((float*)out)[i] = v;
    else          ((__hip_bfloat16*)out)[i] = __float2bfloat16(v);
}

// ---------------- workspace layout (~21.4 MB) ----------------
static constexpr size_t AL(size_t x) { return (x + 255) & ~size_t(255); }
static constexpr size_t OFF_FLAGS  = 0;
static constexpr size_t OFF_COUNTS = OFF_FLAGS + 256;
static constexpr size_t OFF_CURSOR = OFF_COUNTS + AL(NN * 4);
static constexpr size_t OFF_ROWPTR = OFF_CURSOR + AL(NN * 4);
static constexpr size_t OFF_BSUM   = OFF_ROWPTR + AL((NN + 1) * 4);
static constexpr size_t OFF_BOFF   = OFF_BSUM + AL(SCAN_NB * 4);
static constexpr size_t OFF_CSR    = OFF_BOFF + AL(SCAN_NB * 4);
static constexpr size_t OFF_DIS    = OFF_CSR + AL((size_t)NE * 4);
static constexpr size_t OFF_H      = OFF_DIS + AL(NN * 4);                // NN*128 fp8 (reused as NN*64 bf16)
static constexpr size_t OFF_W1F    = OFF_H + AL((size_t)NN * 128);
static constexpr size_t OFF_B1F    = OFF_W1F + AL(16384 * 4);
static constexpr size_t OFF_W2F    = OFF_B1F + AL(128 * 4);
static constexpr size_t OFF_B2F    = OFF_W2F + AL(16384 * 4);
static constexpr size_t OFF_W3F    = OFF_B2F + AL(128 * 4);
static constexpr size_t OFF_B3F    = OFF_W3F + AL(8192 * 4);
static constexpr size_t OFF_WAF    = OFF_B3F + AL(64 * 4);
static constexpr size_t OFF_COLSUM = OFF_WAF + AL(4096 * 4);
static constexpr size_t OFF_POOLED = OFF_COLSUM + AL(64 * 4);
static constexpr size_t OFF_CTX    = OFF_POOLED + AL(64 * 4);
static constexpr size_t WS_NEEDED  = OFF_CTX + AL(64 * 4);   // ~21.4 MB

extern "C" void kernel_launch(void* const* d_in, const int* in_sizes, int n_in,
                              void* d_out, int out_size, void* d_ws, size_t ws_size,
                              hipStream_t stream) {
    const int* ei = (const int*)d_in[0];
    const void* x  = d_in[1];
    const void* W1 = d_in[2];
    const void* b1 = d_in[3];
    const void* W2 = d_in[4];
    const void* b2 = d_in[5];
    const void* W3 = d_in[6];
    const void* b3 = d_in[7];
    const void* Wa = d_in[8];

    char* ws = (char*)d_ws;
    int*   flags  = (int*)(ws + OFF_FLAGS);
    int*   counts = (int*)(ws + OFF_COUNTS);
    int*   cursor = (int*)(ws + OFF_CURSOR);
    int*   rowptr = (int*)(ws + OFF_ROWPTR);
    int*   bsum   = (int*)(ws + OFF_BSUM);
    int*   boff   = (int*)(ws + OFF_BOFF);
    int*   csr    = (int*)(ws + OFF_CSR);
    float* dis    = (float*)(ws + OFF_DIS);
    unsigned char*  H  = (unsigned char*)(ws + OFF_H);
    __hip_bfloat16* Hb = (__hip_bfloat16*)(ws + OFF_H);
    float* W1f    = (float*)(ws + OFF_W1F);
    float* b1f    = (float*)(ws + OFF_B1F);
    float* W2f    = (float*)(ws + OFF_W2F);
    float* b2f    = (float*)(ws + OFF_B2F);
    float* W3f    = (float*)(ws + OFF_W3F);
    float* b3f    = (float*)(ws + OFF_B3F);
    float* Waf    = (float*)(ws + OFF_WAF);
    float* colsum = (float*)(ws + OFF_COLSUM);
    float* pooled = (float*)(ws + OFF_POOLED);
    float* ctx    = (float*)(ws + OFF_CTX);

    unsigned char* G = (unsigned char*)d_out;   // d_out doubles as the ping scratch table

    hipMemsetAsync(counts, 0, NN * 4, stream);
    hipMemsetAsync(cursor, 0, NN * 4, stream);
    hipMemsetAsync(colsum, 0, 64 * 4, stream);
    hipMemsetAsync(pooled, 0, 64 * 4, stream);

    k_probe<<<1, 256, 0, stream>>>((const unsigned short*)x, ei, flags);
    cvt_params<<<64, 256, 0, stream>>>(W1, b1, W2, b2, W3, b3, Wa,
                                       W1f, b1f, W2f, b2f, W3f, b3f, Waf, flags);

    k_count<<<(NE + 255) / 256, 256, 0, stream>>>(ei, counts, flags);
    k_dis<<<(NN + 255) / 256, 256, 0, stream>>>(counts, dis);
    k_scan1<<<SCAN_NB, SCAN_T, 0, stream>>>(counts, bsum);
    k_scan2<<<1, 64, 0, stream>>>(bsum, boff, rowptr);
    k_scan3<<<SCAN_NB, SCAN_T, 0, stream>>>(counts, boff, rowptr);
    k_place<<<(NE + 255) / 256, 256, 0, stream>>>(ei, rowptr, cursor, csr, flags);

    // L1: G = Anorm@x ; H = relu(G@W1 + b1)
    k_aggx<<<NN, 128, 0, stream>>>(x, rowptr, csr, dis, G, flags);
    k_xform<<<(NN + 7) / 8, 128, 0, stream>>>(G, W1f, b1f, H);
    // L2: G = Anorm@H ; H = relu(G@W2 + b2)
    k_agg8<<<NN, 128, 0, stream>>>(H, rowptr, csr, dis, G);
    k_xform<<<(NN + 7) / 8, 128, 0, stream>>>(G, W2f, b2f, H);
    // L3: G = Anorm@H ; Hb = G@W3 + b3 (bf16, overwrites H region)
    k_agg8<<<NN, 128, 0, stream>>>(H, rowptr, csr, dis, G);
    k_xform3<<<(NN + 7) / 8, 64, 0, stream>>>(G, W3f, b3f, Hb);

    // attention pooling on Hb
    k_colsum<<<256, 256, 0, stream>>>(Hb, colsum);
    k_ctx<<<1, 64, 0, stream>>>(colsum, Waf, ctx);
    k_pool<<<256, 256, 0, stream>>>(Hb, ctx, pooled);

    // final output (overwrites the G scratch with real h3 + pooled)
    k_out<<<(6400064 + 255) / 256, 256, 0, stream>>>(Hb, pooled, d_out, flags);
}

// Round 4
// 864.984 us; speedup vs baseline: 1.8209x; 1.8209x over previous
//
#include <hip/hip_runtime.h>
#include <hip/hip_bf16.h>

#define NN 100000
#define NE 1600000
#define SCAN_T 256
#define SCAN_E 1024
#define SCAN_NB ((NN + SCAN_E - 1) / SCAN_E)   // 98

static __device__ __forceinline__ float bf2f(__hip_bfloat16 v) { return __bfloat162float(v); }

// ---------------- fp8 e4m3 encode/decode (validated round 3) ----------------
static __device__ __forceinline__ float f8d(unsigned b) {
    unsigned e = (b >> 3) & 15u, m = b & 7u;
    float mag;
    if (e == 0) mag = (float)m * 0.001953125f;
    else        mag = __uint_as_float(((e + 120u) << 23) | (m << 20));
    return (b & 0x80u) ? -mag : mag;
}
static __device__ __forceinline__ unsigned char f8e(float x) {
    unsigned u = __float_as_uint(x);
    unsigned s = (u >> 31) << 7;
    unsigned au = u & 0x7fffffffu;
    if (au >= 0x43E00000u) return (unsigned char)(s | 0x7Eu);
    if (au <  0x3A800000u) return (unsigned char)s;
    if (au <  0x3C800000u) {
        float a = __uint_as_float(au);
        int m = (int)rintf(a * 512.0f);
        if (m >= 8) return (unsigned char)(s | 0x08u);
        return (unsigned char)(s | (unsigned)m);
    }
    au += 0x80000u;
    if (au >= 0x43E00000u) return (unsigned char)(s | 0x7Eu);
    unsigned e = (au >> 23) - 120u;
    unsigned m = (au >> 20) & 7u;
    return (unsigned char)(s | (e << 3) | m);
}
static __device__ __forceinline__ float bfu(unsigned short w) {
    return __uint_as_float((unsigned)w << 16);
}

// ---------------- dtype probes ----------------
__global__ void k_probe(const unsigned short* __restrict__ xw,
                        const int* __restrict__ ei, int* __restrict__ flags) {
    __shared__ int cnt_nan, odd_nz;
    if (threadIdx.x == 0) { cnt_nan = 0; odd_nz = 0; }
    __syncthreads();
    for (int i = threadIdx.x; i < 65536; i += 256) {
        unsigned short w = xw[i];
        if ((w & 0x7F80u) == 0x7F80u) atomicAdd(&cnt_nan, 1);
    }
    if (threadIdx.x < 256) {
        if (ei[2 * threadIdx.x + 1] != 0) atomicAdd(&odd_nz, 1);
    }
    __syncthreads();
    if (threadIdx.x == 0) {
        flags[0] = (cnt_nan > 0) ? 1 : 0;   // x/weights are f32
        flags[1] = (odd_nz == 0) ? 1 : 0;   // edge_index is int64
    }
}

static __device__ __forceinline__ int e_src(const int* ei, int e, int f64) {
    int v = f64 ? ei[2 * e] : ei[e];
    return min(max(v, 0), NN - 1);
}
static __device__ __forceinline__ int e_dst(const int* ei, int e, int f64) {
    int v = f64 ? ei[2 * (NE + e)] : ei[NE + e];
    return min(max(v, 0), NN - 1);
}
static __device__ __forceinline__ float ldx(const void* p, long long i, int f32) {
    return f32 ? ((const float*)p)[i] : bf2f(((const __hip_bfloat16*)p)[i]);
}

// ---------------- parameter conversion: W -> bf16(ushort), b/Wa -> f32 --------
__global__ void cvt_params(const void* W1, const void* b1, const void* W2, const void* b2,
                           const void* W3, const void* b3, const void* Wa,
                           unsigned short* W1b, unsigned short* W2b, unsigned short* W3b,
                           float* b1f, float* b2f, float* b3f, float* Waf,
                           const int* flags) {
    int i = blockIdx.x * blockDim.x + threadIdx.x;
    int f = flags[0];
    if (i < 16384) {
        W1b[i] = __bfloat16_as_ushort(__float2bfloat16(ldx(W1, i, f)));
        W2b[i] = __bfloat16_as_ushort(__float2bfloat16(ldx(W2, i, f)));
    }
    if (i < 8192)  W3b[i] = __bfloat16_as_ushort(__float2bfloat16(ldx(W3, i, f)));
    if (i < 4096)  Waf[i] = ldx(Wa, i, f);
    if (i < 128)   { b1f[i] = ldx(b1, i, f); b2f[i] = ldx(b2, i, f); }
    if (i < 64)    b3f[i] = ldx(b3, i, f);
}

// ---------------- x -> fp8 table P ----------------
__global__ void k_cvtx(const void* __restrict__ x, unsigned char* __restrict__ P,
                       const int* __restrict__ flags) {
    int i = blockIdx.x * blockDim.x + threadIdx.x;      // one uint (4 elems) per thread
    if (i >= (NN * 128) / 4) return;
    unsigned pk;
    if (flags[0]) {
        float4 v = ((const float4*)x)[i];
        pk = (unsigned)f8e(v.x) | ((unsigned)f8e(v.y) << 8) |
             ((unsigned)f8e(v.z) << 16) | ((unsigned)f8e(v.w) << 24);
    } else {
        ushort4 v = ((const ushort4*)x)[i];
        pk = (unsigned)f8e(bfu(v.x)) | ((unsigned)f8e(bfu(v.y)) << 8) |
             ((unsigned)f8e(bfu(v.z)) << 16) | ((unsigned)f8e(bfu(v.w)) << 24);
    }
    ((unsigned*)P)[i] = pk;
}

// ---------------- degree count + dis ----------------
__global__ void k_count(const int* __restrict__ ei, int* __restrict__ counts,
                        const int* __restrict__ flags) {
    int e = blockIdx.x * blockDim.x + threadIdx.x;
    if (e < NE) atomicAdd(&counts[e_dst(ei, e, flags[1])], 1);
}

__global__ void k_dis(const int* __restrict__ counts, float* __restrict__ dis) {
    int n = blockIdx.x * blockDim.x + threadIdx.x;
    if (n < NN) dis[n] = rsqrtf((float)counts[n] + 1.0f);
}

// ---------------- exclusive scan -> rowptr ----------------
__global__ void k_scan1(const int* __restrict__ counts, int* __restrict__ bsum) {
    __shared__ int sd[SCAN_T];
    int b = blockIdx.x, t = threadIdx.x;
    int base = b * SCAN_E + t * 4;
    int s = 0;
#pragma unroll
    for (int i = 0; i < 4; i++) { int idx = base + i; if (idx < NN) s += counts[idx]; }
    sd[t] = s; __syncthreads();
    for (int o = SCAN_T / 2; o > 0; o >>= 1) {
        if (t < o) sd[t] += sd[t + o];
        __syncthreads();
    }
    if (t == 0) bsum[b] = sd[0];
}

__global__ void k_scan2(const int* __restrict__ bsum, int* __restrict__ boff,
                        int* __restrict__ rowptr) {
    if (threadIdx.x == 0 && blockIdx.x == 0) {
        int run = 0;
        for (int b = 0; b < SCAN_NB; b++) { boff[b] = run; run += bsum[b]; }
        rowptr[NN] = run;
    }
}

__global__ void k_scan3(const int* __restrict__ counts, const int* __restrict__ boff,
                        int* __restrict__ rowptr) {
    __shared__ int sd[SCAN_T];
    int b = blockIdx.x, t = threadIdx.x;
    int base = b * SCAN_E + t * 4;
    int v[4]; int s = 0;
#pragma unroll
    for (int i = 0; i < 4; i++) { int idx = base + i; v[i] = (idx < NN) ? counts[idx] : 0; s += v[i]; }
    sd[t] = s; __syncthreads();
    for (int o = 1; o < SCAN_T; o <<= 1) {
        int add = (t >= o) ? sd[t - o] : 0;
        __syncthreads();
        sd[t] += add;
        __syncthreads();
    }
    int run = sd[t] - s + boff[b];
#pragma unroll
    for (int i = 0; i < 4; i++) {
        int idx = base + i;
        if (idx < NN) { rowptr[idx] = run; run += v[i]; }
    }
}

__global__ void k_place(const int* __restrict__ ei, const int* __restrict__ rowptr,
                        int* __restrict__ cursor, int* __restrict__ csr_src,
                        const int* __restrict__ flags) {
    int e = blockIdx.x * blockDim.x + threadIdx.x;
    if (e < NE) {
        int f64 = flags[1];
        int d = e_dst(ei, e, f64);
        int p = rowptr[d] + atomicAdd(&cursor[d], 1);
        p = min(max(p, 0), NE - 1);
        csr_src[p] = e_src(ei, e, f64);
    }
}

// ---------------- GEMM 128x128: O = A(fp8) @ W(bf16 LDS), fp8 out ------------
__global__ __launch_bounds__(256) void k_xform128(const unsigned char* __restrict__ A,
                                                  const unsigned short* __restrict__ Wb,
                                                  unsigned char* __restrict__ O) {
    __shared__ float rows[32 * 129];
    __shared__ unsigned short wl[128 * 128];
    int t = threadIdx.x;
    int n0 = blockIdx.x * 32;
    // stage W (32 KB): 2048 uint4, 8 per thread
    {
        const uint4* wg = (const uint4*)Wb;
        uint4* wld = (uint4*)wl;
        for (int i = t; i < 2048; i += 256) wld[i] = wg[i];
    }
    // stage 32 rows (4 KB fp8): one uint4 (16 bytes) per thread
    {
        uint4 v = ((const uint4*)(A + (size_t)n0 * 128))[t];
        int r = t >> 3, c = (t & 7) * 16;
        float* dstp = &rows[r * 129 + c];
        unsigned b4[4] = {v.x, v.y, v.z, v.w};
#pragma unroll
        for (int q = 0; q < 4; q++) {
            unsigned u = b4[q];
            dstp[q * 4 + 0] = f8d(u & 255u);
            dstp[q * 4 + 1] = f8d((u >> 8) & 255u);
            dstp[q * 4 + 2] = f8d((u >> 16) & 255u);
            dstp[q * 4 + 3] = f8d(u >> 24);
        }
    }
    __syncthreads();
    int cg = t & 31, rg = t >> 5;
    int c0 = cg * 4, r0 = rg * 4;
    float acc[4][4] = {};
#pragma unroll 4
    for (int k = 0; k < 128; k++) {
        float a0 = rows[(r0 + 0) * 129 + k];
        float a1 = rows[(r0 + 1) * 129 + k];
        float a2 = rows[(r0 + 2) * 129 + k];
        float a3 = rows[(r0 + 3) * 129 + k];
        ushort4 wv = *(const ushort4*)&wl[k * 128 + c0];
        float w0 = bfu(wv.x), w1 = bfu(wv.y), w2 = bfu(wv.z), w3 = bfu(wv.w);
        acc[0][0] += a0 * w0; acc[0][1] += a0 * w1; acc[0][2] += a0 * w2; acc[0][3] += a0 * w3;
        acc[1][0] += a1 * w0; acc[1][1] += a1 * w1; acc[1][2] += a1 * w2; acc[1][3] += a1 * w3;
        acc[2][0] += a2 * w0; acc[2][1] += a2 * w1; acc[2][2] += a2 * w2; acc[2][3] += a2 * w3;
        acc[3][0] += a3 * w0; acc[3][1] += a3 * w1; acc[3][2] += a3 * w2; acc[3][3] += a3 * w3;
    }
#pragma unroll
    for (int i = 0; i < 4; i++) {
        unsigned p = (unsigned)f8e(acc[i][0]) | ((unsigned)f8e(acc[i][1]) << 8) |
                     ((unsigned)f8e(acc[i][2]) << 16) | ((unsigned)f8e(acc[i][3]) << 24);
        *(unsigned*)(O + (size_t)(n0 + r0 + i) * 128 + c0) = p;
    }
}

// ---------------- GEMM 128x64: O = A(fp8) @ W3(bf16 LDS), fp8 out ------------
__global__ __launch_bounds__(256) void k_xform64(const unsigned char* __restrict__ A,
                                                 const unsigned short* __restrict__ Wb,
                                                 unsigned char* __restrict__ O) {
    __shared__ float rows[64 * 129];
    __shared__ unsigned short wl[128 * 64];
    int t = threadIdx.x;
    int n0 = blockIdx.x * 64;
    {
        const uint4* wg = (const uint4*)Wb;
        uint4* wld = (uint4*)wl;
        for (int i = t; i < 1024; i += 256) wld[i] = wg[i];
    }
    // stage 64 rows (8 KB fp8): two uint4 per thread; thread t covers bytes [t*32, t*32+32) = row t>>2
    {
        int r = t >> 2, c = (t & 3) * 32;
        bool ok = (n0 + r) < NN;
        const uint4* ap = (const uint4*)(A + (size_t)(n0 + r) * 128 + c);
#pragma unroll
        for (int h = 0; h < 2; h++) {
            uint4 v = ok ? ap[h] : make_uint4(0, 0, 0, 0);
            float* dstp = &rows[r * 129 + c + h * 16];
            unsigned b4[4] = {v.x, v.y, v.z, v.w};
#pragma unroll
            for (int q = 0; q < 4; q++) {
                unsigned u = b4[q];
                dstp[q * 4 + 0] = f8d(u & 255u);
                dstp[q * 4 + 1] = f8d((u >> 8) & 255u);
                dstp[q * 4 + 2] = f8d((u >> 16) & 255u);
                dstp[q * 4 + 3] = f8d(u >> 24);
            }
        }
    }
    __syncthreads();
    int cg = t & 15, rg = t >> 4;       // 16 col-groups x 4 = 64 cols ; 16 row-groups x 4 = 64 rows
    int c0 = cg * 4, r0 = rg * 4;
    float acc[4][4] = {};
#pragma unroll 4
    for (int k = 0; k < 128; k++) {
        float a0 = rows[(r0 + 0) * 129 + k];
        float a1 = rows[(r0 + 1) * 129 + k];
        float a2 = rows[(r0 + 2) * 129 + k];
        float a3 = rows[(r0 + 3) * 129 + k];
        ushort4 wv = *(const ushort4*)&wl[k * 64 + c0];
        float w0 = bfu(wv.x), w1 = bfu(wv.y), w2 = bfu(wv.z), w3 = bfu(wv.w);
        acc[0][0] += a0 * w0; acc[0][1] += a0 * w1; acc[0][2] += a0 * w2; acc[0][3] += a0 * w3;
        acc[1][0] += a1 * w0; acc[1][1] += a1 * w1; acc[1][2] += a1 * w2; acc[1][3] += a1 * w3;
        acc[2][0] += a2 * w0; acc[2][1] += a2 * w1; acc[2][2] += a2 * w2; acc[2][3] += a2 * w3;
        acc[3][0] += a3 * w0; acc[3][1] += a3 * w1; acc[3][2] += a3 * w2; acc[3][3] += a3 * w3;
    }
#pragma unroll
    for (int i = 0; i < 4; i++) {
        int n = n0 + r0 + i;
        if (n < NN) {
            unsigned p = (unsigned)f8e(acc[i][0]) | ((unsigned)f8e(acc[i][1]) << 8) |
                         ((unsigned)f8e(acc[i][2]) << 16) | ((unsigned)f8e(acc[i][3]) << 24);
            *(unsigned*)(O + (size_t)n * 64 + c0) = p;
        }
    }
}

// ---------------- agg v2, F=128: H = relu?(Anorm @ T + b), fp8 -> fp8 --------
// wave per node; lanes pre-stage 64 indices+weights, readlane-broadcast
template <bool RELU>
__global__ __launch_bounds__(256) void k_agg128(const unsigned char* __restrict__ T,
                                                const int* __restrict__ rowptr,
                                                const int* __restrict__ csr,
                                                const float* __restrict__ dis,
                                                const float* __restrict__ bias,
                                                unsigned char* __restrict__ H) {
    int n = blockIdx.x * 4 + (threadIdx.x >> 6);
    int lane = threadIdx.x & 63;
    float dn = dis[n];
    int s0 = rowptr[n], s1 = rowptr[n + 1];
    s0 = min(max(s0, 0), NE); s1 = min(max(s1, s0), NE);
    unsigned short rself = *(const unsigned short*)(T + (size_t)n * 128 + lane * 2);
    float a0 = f8d(rself & 255u) * (dn * dn) + bias[2 * lane];
    float a1 = f8d(rself >> 8)   * (dn * dn) + bias[2 * lane + 1];
    float b0 = 0.0f, b1 = 0.0f;
    for (int base = s0; base < s1; base += 64) {
        int m = min(64, s1 - base);
        int idx = 0; float wv = 0.0f;
        if (lane < m) {
            idx = min(max(csr[base + lane], 0), NN - 1);
            wv = dis[idx] * dn;
        }
        unsigned wbits = __float_as_uint(wv);
        int j = 0;
        for (; j + 2 <= m; j += 2) {
            int sa = __builtin_amdgcn_readlane(idx, j);
            int sb = __builtin_amdgcn_readlane(idx, j + 1);
            float wa = __uint_as_float(__builtin_amdgcn_readlane(wbits, j));
            float wb = __uint_as_float(__builtin_amdgcn_readlane(wbits, j + 1));
            unsigned short ra = *(const unsigned short*)(T + (size_t)sa * 128 + lane * 2);
            unsigned short rb = *(const unsigned short*)(T + (size_t)sb * 128 + lane * 2);
            a0 += f8d(ra & 255u) * wa; a1 += f8d(ra >> 8) * wa;
            b0 += f8d(rb & 255u) * wb; b1 += f8d(rb >> 8) * wb;
        }
        if (j < m) {
            int sa = __builtin_amdgcn_readlane(idx, j);
            float wa = __uint_as_float(__builtin_amdgcn_readlane(wbits, j));
            unsigned short ra = *(const unsigned short*)(T + (size_t)sa * 128 + lane * 2);
            a0 += f8d(ra & 255u) * wa; a1 += f8d(ra >> 8) * wa;
        }
    }
    a0 += b0; a1 += b1;
    if (RELU) { a0 = fmaxf(a0, 0.0f); a1 = fmaxf(a1, 0.0f); }
    unsigned short pk = (unsigned short)f8e(a0) | ((unsigned short)f8e(a1) << 8);
    *(unsigned short*)(H + (size_t)n * 128 + lane * 2) = pk;
}

// ---------------- agg v2, F=64 final: h3 = Anorm @ T3 + b3 -> bf16 -----------
__global__ __launch_bounds__(256) void k_agg64(const unsigned char* __restrict__ T,
                                               const int* __restrict__ rowptr,
                                               const int* __restrict__ csr,
                                               const float* __restrict__ dis,
                                               const float* __restrict__ bias,
                                               unsigned short* __restrict__ Hb) {
    int n = blockIdx.x * 4 + (threadIdx.x >> 6);
    int lane = threadIdx.x & 63;
    float dn = dis[n];
    int s0 = rowptr[n], s1 = rowptr[n + 1];
    s0 = min(max(s0, 0), NE); s1 = min(max(s1, s0), NE);
    float a0 = f8d(T[(size_t)n * 64 + lane]) * (dn * dn) + bias[lane];
    float b0 = 0.0f;
    for (int base = s0; base < s1; base += 64) {
        int m = min(64, s1 - base);
        int idx = 0; float wv = 0.0f;
        if (lane < m) {
            idx = min(max(csr[base + lane], 0), NN - 1);
            wv = dis[idx] * dn;
        }
        unsigned wbits = __float_as_uint(wv);
        int j = 0;
        for (; j + 2 <= m; j += 2) {
            int sa = __builtin_amdgcn_readlane(idx, j);
            int sb = __builtin_amdgcn_readlane(idx, j + 1);
            float wa = __uint_as_float(__builtin_amdgcn_readlane(wbits, j));
            float wb = __uint_as_float(__builtin_amdgcn_readlane(wbits, j + 1));
            unsigned char ra = T[(size_t)sa * 64 + lane];
            unsigned char rb = T[(size_t)sb * 64 + lane];
            a0 += f8d(ra) * wa;
            b0 += f8d(rb) * wb;
        }
        if (j < m) {
            int sa = __builtin_amdgcn_readlane(idx, j);
            float wa = __uint_as_float(__builtin_amdgcn_readlane(wbits, j));
            a0 += f8d(T[(size_t)sa * 64 + lane]) * wa;
        }
    }
    a0 += b0;
    Hb[(size_t)n * 64 + lane] = __bfloat16_as_ushort(__float2bfloat16(a0));
}

// ---------------- attention pooling on Hb (bf16-as-ushort) ----------------
__global__ void k_colsum(const unsigned short* __restrict__ h3, float* __restrict__ colsum) {
    int lane = threadIdx.x & 63;
    int wave = (blockIdx.x * blockDim.x + threadIdx.x) >> 6;
    int nw = (gridDim.x * blockDim.x) >> 6;
    float acc = 0.0f;
    for (int n = wave; n < NN; n += nw) acc += bfu(h3[(size_t)n * 64 + lane]);
    __shared__ float sd[256];
    sd[threadIdx.x] = acc; __syncthreads();
    if (threadIdx.x < 64)
        atomicAdd(&colsum[threadIdx.x],
                  sd[threadIdx.x] + sd[threadIdx.x + 64] + sd[threadIdx.x + 128] + sd[threadIdx.x + 192]);
}

__global__ void k_ctx(const float* __restrict__ colsum, const float* __restrict__ Wa,
                      float* __restrict__ ctx) {
    __shared__ float ms[64];
    int j = threadIdx.x;
    ms[j] = colsum[j] * (1.0f / NN);
    __syncthreads();
    float s = 0.0f;
#pragma unroll
    for (int k = 0; k < 64; k++) s += ms[k] * Wa[k * 64 + j];
    ctx[j] = tanhf(s);
}

__global__ void k_pool(const unsigned short* __restrict__ h3, const float* __restrict__ ctx,
                       float* __restrict__ pooled) {
    int lane = threadIdx.x & 63;
    int wave = (blockIdx.x * blockDim.x + threadIdx.x) >> 6;
    int nw = (gridDim.x * blockDim.x) >> 6;
    float c = ctx[lane];
    float acc = 0.0f;
    for (int n = wave; n < NN; n += nw) {
        float v = bfu(h3[(size_t)n * 64 + lane]);
        float p = v * c;
#pragma unroll
        for (int m = 32; m > 0; m >>= 1) p += __shfl_xor(p, m, 64);
        float score = 1.0f / (1.0f + expf(-p));
        acc += score * v;
    }
    __shared__ float sd[256];
    sd[threadIdx.x] = acc; __syncthreads();
    if (threadIdx.x < 64)
        atomicAdd(&pooled[threadIdx.x],
                  sd[threadIdx.x] + sd[threadIdx.x + 64] + sd[threadIdx.x + 128] + sd[threadIdx.x + 192]);
}

// ---------------- final output write ----------------
__global__ void k_out(const unsigned short* __restrict__ h3, const float* __restrict__ pooled,
                      void* __restrict__ out, const int* __restrict__ flags) {
    long long i = (long long)blockIdx.x * blockDim.x + threadIdx.x;
    if (i >= 6400064LL) return;
    float v = (i < 6400000LL) ? bfu(h3[i]) : pooled[i - 6400000LL];
    if (flags[0]) ((float*)out)[i] = v;
    else          ((unsigned short*)out)[i] = __bfloat16_as_ushort(__float2bfloat16(v));
}

// ---------------- workspace layout (~21.5 MB) ----------------
static constexpr size_t AL(size_t x) { return (x + 255) & ~size_t(255); }
static constexpr size_t OFF_FLAGS  = 0;
static constexpr size_t OFF_COUNTS = OFF_FLAGS + 256;
static constexpr size_t OFF_CURSOR = OFF_COUNTS + AL(NN * 4);
static constexpr size_t OFF_ROWPTR = OFF_CURSOR + AL(NN * 4);
static constexpr size_t OFF_BSUM   = OFF_ROWPTR + AL((NN + 1) * 4);
static constexpr size_t OFF_BOFF   = OFF_BSUM + AL(SCAN_NB * 4);
static constexpr size_t OFF_CSR    = OFF_BOFF + AL(SCAN_NB * 4);
static constexpr size_t OFF_DIS    = OFF_CSR + AL((size_t)NE * 4);
static constexpr size_t OFF_P      = OFF_DIS + AL(NN * 4);               // NN*128 fp8 / NN*64 bf16
static constexpr size_t OFF_W1B    = OFF_P + AL((size_t)NN * 128);
static constexpr size_t OFF_W2B    = OFF_W1B + AL(16384 * 2);
static constexpr size_t OFF_W3B    = OFF_W2B + AL(16384 * 2);
static constexpr size_t OFF_B1F    = OFF_W3B + AL(8192 * 2);
static constexpr size_t OFF_B2F    = OFF_B1F + AL(128 * 4);
static constexpr size_t OFF_B3F    = OFF_B2F + AL(128 * 4);
static constexpr size_t OFF_WAF    = OFF_B3F + AL(64 * 4);
static constexpr size_t OFF_COLSUM = OFF_WAF + AL(4096 * 4);
static constexpr size_t OFF_POOLED = OFF_COLSUM + AL(64 * 4);
static constexpr size_t OFF_CTX    = OFF_POOLED + AL(64 * 4);

extern "C" void kernel_launch(void* const* d_in, const int* in_sizes, int n_in,
                              void* d_out, int out_size, void* d_ws, size_t ws_size,
                              hipStream_t stream) {
    const int* ei = (const int*)d_in[0];
    const void* x  = d_in[1];
    const void* W1 = d_in[2];
    const void* b1 = d_in[3];
    const void* W2 = d_in[4];
    const void* b2 = d_in[5];
    const void* W3 = d_in[6];
    const void* b3 = d_in[7];
    const void* Wa = d_in[8];

    char* ws = (char*)d_ws;
    int*   flags  = (int*)(ws + OFF_FLAGS);
    int*   counts = (int*)(ws + OFF_COUNTS);
    int*   cursor = (int*)(ws + OFF_CURSOR);
    int*   rowptr = (int*)(ws + OFF_ROWPTR);
    int*   bsum   = (int*)(ws + OFF_BSUM);
    int*   boff   = (int*)(ws + OFF_BOFF);
    int*   csr    = (int*)(ws + OFF_CSR);
    float* dis    = (float*)(ws + OFF_DIS);
    unsigned char*  P   = (unsigned char*)(ws + OFF_P);
    unsigned short* Hb  = (unsigned short*)(ws + OFF_P);   // reuse as bf16 after L3 xform
    unsigned short* W1b = (unsigned short*)(ws + OFF_W1B);
    unsigned short* W2b = (unsigned short*)(ws + OFF_W2B);
    unsigned short* W3b = (unsigned short*)(ws + OFF_W3B);
    float* b1f    = (float*)(ws + OFF_B1F);
    float* b2f    = (float*)(ws + OFF_B2F);
    float* b3f    = (float*)(ws + OFF_B3F);
    float* Waf    = (float*)(ws + OFF_WAF);
    float* colsum = (float*)(ws + OFF_COLSUM);
    float* pooled = (float*)(ws + OFF_POOLED);
    float* ctx    = (float*)(ws + OFF_CTX);

    unsigned char* Q = (unsigned char*)d_out;   // d_out doubles as the T-scratch (12.8 MB)

    hipMemsetAsync(counts, 0, NN * 4, stream);
    hipMemsetAsync(cursor, 0, NN * 4, stream);
    hipMemsetAsync(colsum, 0, 64 * 4, stream);
    hipMemsetAsync(pooled, 0, 64 * 4, stream);

    k_probe<<<1, 256, 0, stream>>>((const unsigned short*)x, ei, flags);
    cvt_params<<<64, 256, 0, stream>>>(W1, b1, W2, b2, W3, b3, Wa,
                                       W1b, W2b, W3b, b1f, b2f, b3f, Waf, flags);

    k_count<<<(NE + 255) / 256, 256, 0, stream>>>(ei, counts, flags);
    k_dis<<<(NN + 255) / 256, 256, 0, stream>>>(counts, dis);
    k_scan1<<<SCAN_NB, SCAN_T, 0, stream>>>(counts, bsum);
    k_scan2<<<1, 64, 0, stream>>>(bsum, boff, rowptr);
    k_scan3<<<SCAN_NB, SCAN_T, 0, stream>>>(counts, boff, rowptr);
    k_place<<<(NE + 255) / 256, 256, 0, stream>>>(ei, rowptr, cursor, csr, flags);

    // x -> fp8 P
    k_cvtx<<<(NN * 128 / 4 + 255) / 256, 256, 0, stream>>>(x, P, flags);

    // L1: T = P@W1 (Q) ; P = relu(Anorm@T + b1)
    k_xform128<<<NN / 32, 256, 0, stream>>>(P, W1b, Q);
    k_agg128<true><<<NN / 4, 256, 0, stream>>>(Q, rowptr, csr, dis, b1f, P);
    // L2
    k_xform128<<<NN / 32, 256, 0, stream>>>(P, W2b, Q);
    k_agg128<true><<<NN / 4, 256, 0, stream>>>(Q, rowptr, csr, dis, b2f, P);
    // L3: T3 = P@W3 (Q, 64 cols) ; Hb = Anorm@T3 + b3 (bf16, overwrites P)
    k_xform64<<<(NN + 63) / 64, 256, 0, stream>>>(P, W3b, Q);
    k_agg64<<<NN / 4, 256, 0, stream>>>(Q, rowptr, csr, dis, b3f, Hb);

    // attention pooling
    k_colsum<<<256, 256, 0, stream>>>(Hb, colsum);
    k_ctx<<<1, 64, 0, stream>>>(colsum, Waf, ctx);
    k_pool<<<256, 256, 0, stream>>>(Hb, ctx, pooled);

    // final output
    k_out<<<(6400064 + 255) / 256, 256, 0, stream>>>(Hb, pooled, d_out, flags);
}

// Round 5
// 675.457 us; speedup vs baseline: 2.3318x; 1.2806x over previous
//
#include <hip/hip_runtime.h>
#include <hip/hip_bf16.h>

#define NN 100000
#define NE 1600000
#define SCAN_T 256
#define SCAN_E 1024
#define SCAN_NB ((NN + SCAN_E - 1) / SCAN_E)   // 98

#if defined(__has_builtin)
#  if __has_builtin(__builtin_amdgcn_cvt_pk_f32_fp8) && \
      __has_builtin(__builtin_amdgcn_cvt_pk_fp8_f32) && \
      __has_builtin(__builtin_amdgcn_cvt_f32_fp8)
#    define HWF8 1
#  endif
#endif

typedef float f32x2 __attribute__((ext_vector_type(2)));

static __device__ __forceinline__ float bf2f(__hip_bfloat16 v) { return __bfloat162float(v); }
static __device__ __forceinline__ float bfu(unsigned short w) {
    return __uint_as_float((unsigned)w << 16);
}

// ---------------- fp8 e4m3 software codec (fallback, validated r3/r4) ---------
static __device__ __forceinline__ float f8d_sw(unsigned b) {
    unsigned e = (b >> 3) & 15u, m = b & 7u;
    float mag;
    if (e == 0) mag = (float)m * 0.001953125f;
    else        mag = __uint_as_float(((e + 120u) << 23) | (m << 20));
    return (b & 0x80u) ? -mag : mag;
}
static __device__ __forceinline__ unsigned char f8e_sw(float x) {
    unsigned u = __float_as_uint(x);
    unsigned s = (u >> 31) << 7;
    unsigned au = u & 0x7fffffffu;
    if (au >= 0x43E00000u) return (unsigned char)(s | 0x7Eu);
    if (au <  0x3A800000u) return (unsigned char)s;
    if (au <  0x3C800000u) {
        float a = __uint_as_float(au);
        int m = (int)rintf(a * 512.0f);
        if (m >= 8) return (unsigned char)(s | 0x08u);
        return (unsigned char)(s | (unsigned)m);
    }
    au += 0x80000u;
    if (au >= 0x43E00000u) return (unsigned char)(s | 0x7Eu);
    unsigned e = (au >> 23) - 120u;
    unsigned m = (au >> 20) & 7u;
    return (unsigned char)(s | (e << 3) | m);
}

// ---------------- fp8 helpers (HW if available) ----------------
static __device__ __forceinline__ float f8d1(unsigned b) {
#ifdef HWF8
    return __builtin_amdgcn_cvt_f32_fp8((int)b, 0);
#else
    return f8d_sw(b);
#endif
}
static __device__ __forceinline__ void f8d2(unsigned short v, float& x0, float& x1) {
#ifdef HWF8
    f32x2 r = __builtin_amdgcn_cvt_pk_f32_fp8((int)(unsigned)v, false);
    x0 = r.x; x1 = r.y;
#else
    x0 = f8d_sw(v & 255u); x1 = f8d_sw(v >> 8);
#endif
}
static __device__ __forceinline__ void f8d4(unsigned u, float* o) {
#ifdef HWF8
    f32x2 lo = __builtin_amdgcn_cvt_pk_f32_fp8((int)u, false);
    f32x2 hi = __builtin_amdgcn_cvt_pk_f32_fp8((int)u, true);
    o[0] = lo.x; o[1] = lo.y; o[2] = hi.x; o[3] = hi.y;
#else
    o[0] = f8d_sw(u & 255u); o[1] = f8d_sw((u >> 8) & 255u);
    o[2] = f8d_sw((u >> 16) & 255u); o[3] = f8d_sw(u >> 24);
#endif
}
static __device__ __forceinline__ unsigned short f8e2(float a, float b) {
#ifdef HWF8
    float ca = fminf(fmaxf(a, -448.0f), 448.0f);
    float cb = fminf(fmaxf(b, -448.0f), 448.0f);
    int p = __builtin_amdgcn_cvt_pk_fp8_f32(ca, cb, 0, false);
    return (unsigned short)(p & 0xFFFF);
#else
    return (unsigned short)f8e_sw(a) | ((unsigned short)f8e_sw(b) << 8);
#endif
}

// ---------------- dtype probes (parallel) ----------------
__global__ void k_probe1(const unsigned short* __restrict__ xw,
                         const int* __restrict__ ei, int* __restrict__ raw) {
    int i = blockIdx.x * 256 + threadIdx.x;    // 65536 probes
    int nan = ((xw[i] & 0x7F80u) == 0x7F80u) ? 1 : 0;
    int odd = (ei[2 * i + 1] != 0) ? 1 : 0;
    unsigned long long bn = __ballot(nan);
    unsigned long long bo = __ballot(odd);
    if ((threadIdx.x & 63) == 0) {
        if (bn) atomicAdd(&raw[0], __popcll(bn));
        if (bo) atomicAdd(&raw[1], __popcll(bo));
    }
}
__global__ void k_probe2(const int* __restrict__ raw, int* __restrict__ flags) {
    if (threadIdx.x == 0) {
        flags[0] = (raw[0] > 0) ? 1 : 0;   // x/weights are f32
        flags[1] = (raw[1] == 0) ? 1 : 0;  // edge_index is int64
    }
}

static __device__ __forceinline__ int e_src(const int* ei, int e, int f64) {
    int v = f64 ? ei[2 * e] : ei[e];
    return min(max(v, 0), NN - 1);
}
static __device__ __forceinline__ int e_dst(const int* ei, int e, int f64) {
    int v = f64 ? ei[2 * (NE + e)] : ei[NE + e];
    return min(max(v, 0), NN - 1);
}
static __device__ __forceinline__ float ldx(const void* p, long long i, int f32) {
    return f32 ? ((const float*)p)[i] : bf2f(((const __hip_bfloat16*)p)[i]);
}

// ---------------- parameter conversion: W -> bf16(ushort), b/Wa -> f32 --------
__global__ void cvt_params(const void* W1, const void* b1, const void* W2, const void* b2,
                           const void* W3, const void* b3, const void* Wa,
                           unsigned short* W1b, unsigned short* W2b, unsigned short* W3b,
                           float* b1f, float* b2f, float* b3f, float* Waf,
                           const int* flags) {
    int i = blockIdx.x * blockDim.x + threadIdx.x;
    int f = flags[0];
    if (i < 16384) {
        W1b[i] = __bfloat16_as_ushort(__float2bfloat16(ldx(W1, i, f)));
        W2b[i] = __bfloat16_as_ushort(__float2bfloat16(ldx(W2, i, f)));
    }
    if (i < 8192)  W3b[i] = __bfloat16_as_ushort(__float2bfloat16(ldx(W3, i, f)));
    if (i < 4096)  Waf[i] = ldx(Wa, i, f);
    if (i < 128)   { b1f[i] = ldx(b1, i, f); b2f[i] = ldx(b2, i, f); }
    if (i < 64)    b3f[i] = ldx(b3, i, f);
}

// ---------------- x -> fp8 table P ----------------
__global__ void k_cvtx(const void* __restrict__ x, unsigned char* __restrict__ P,
                       const int* __restrict__ flags) {
    int i = blockIdx.x * blockDim.x + threadIdx.x;      // one uint (4 elems) per thread
    if (i >= (NN * 128) / 4) return;
    unsigned pk;
    if (flags[0]) {
        float4 v = ((const float4*)x)[i];
        pk = (unsigned)f8e2(v.x, v.y) | ((unsigned)f8e2(v.z, v.w) << 16);
    } else {
        ushort4 v = ((const ushort4*)x)[i];
        pk = (unsigned)f8e2(bfu(v.x), bfu(v.y)) | ((unsigned)f8e2(bfu(v.z), bfu(v.w)) << 16);
    }
    ((unsigned*)P)[i] = pk;
}

// ---------------- degree count + dis ----------------
__global__ void k_count(const int* __restrict__ ei, int* __restrict__ counts,
                        const int* __restrict__ flags) {
    int e = blockIdx.x * blockDim.x + threadIdx.x;
    if (e < NE) atomicAdd(&counts[e_dst(ei, e, flags[1])], 1);
}

__global__ void k_dis(const int* __restrict__ counts, float* __restrict__ dis) {
    int n = blockIdx.x * blockDim.x + threadIdx.x;
    if (n < NN) dis[n] = rsqrtf((float)counts[n] + 1.0f);
}

// ---------------- exclusive scan -> rowptr ----------------
__global__ void k_scan1(const int* __restrict__ counts, int* __restrict__ bsum) {
    __shared__ int sd[SCAN_T];
    int b = blockIdx.x, t = threadIdx.x;
    int base = b * SCAN_E + t * 4;
    int s = 0;
#pragma unroll
    for (int i = 0; i < 4; i++) { int idx = base + i; if (idx < NN) s += counts[idx]; }
    sd[t] = s; __syncthreads();
    for (int o = SCAN_T / 2; o > 0; o >>= 1) {
        if (t < o) sd[t] += sd[t + o];
        __syncthreads();
    }
    if (t == 0) bsum[b] = sd[0];
}

__global__ void k_scan2(const int* __restrict__ bsum, int* __restrict__ boff,
                        int* __restrict__ rowptr) {
    if (threadIdx.x == 0 && blockIdx.x == 0) {
        int run = 0;
        for (int b = 0; b < SCAN_NB; b++) { boff[b] = run; run += bsum[b]; }
        rowptr[NN] = run;
    }
}

__global__ void k_scan3(const int* __restrict__ counts, const int* __restrict__ boff,
                        int* __restrict__ rowptr) {
    __shared__ int sd[SCAN_T];
    int b = blockIdx.x, t = threadIdx.x;
    int base = b * SCAN_E + t * 4;
    int v[4]; int s = 0;
#pragma unroll
    for (int i = 0; i < 4; i++) { int idx = base + i; v[i] = (idx < NN) ? counts[idx] : 0; s += v[i]; }
    sd[t] = s; __syncthreads();
    for (int o = 1; o < SCAN_T; o <<= 1) {
        int add = (t >= o) ? sd[t - o] : 0;
        __syncthreads();
        sd[t] += add;
        __syncthreads();
    }
    int run = sd[t] - s + boff[b];
#pragma unroll
    for (int i = 0; i < 4; i++) {
        int idx = base + i;
        if (idx < NN) { rowptr[idx] = run; run += v[i]; }
    }
}

__global__ void k_place(const int* __restrict__ ei, const int* __restrict__ rowptr,
                        int* __restrict__ cursor, int* __restrict__ csr_src,
                        const int* __restrict__ flags) {
    int e = blockIdx.x * blockDim.x + threadIdx.x;
    if (e < NE) {
        int f64 = flags[1];
        int d = e_dst(ei, e, f64);
        int p = rowptr[d] + atomicAdd(&cursor[d], 1);
        p = min(max(p, 0), NE - 1);
        csr_src[p] = e_src(ei, e, f64);
    }
}

// ---------------- GEMM 128x128: O = A(fp8) @ W(bf16 LDS), fp8 out ------------
// A-tile transposed in LDS (k-major, pad 36) -> ds_read_b128 per k-step.
__global__ __launch_bounds__(256) void k_xform128(const unsigned char* __restrict__ A,
                                                  const unsigned short* __restrict__ Wb,
                                                  unsigned char* __restrict__ O) {
    __shared__ float rowsT[128 * 36];          // [k][r], 18.4 KB
    __shared__ unsigned short wl[128 * 128];   // 32 KB
    int t = threadIdx.x;
    int n0 = blockIdx.x * 32;
    {
        const uint4* wg = (const uint4*)Wb;
        uint4* wld = (uint4*)wl;
        for (int i = t; i < 2048; i += 256) wld[i] = wg[i];
    }
    {
        uint4 v = ((const uint4*)(A + (size_t)n0 * 128))[t];
        int r = t >> 3, cb = (t & 7) * 16;
        unsigned b4[4] = {v.x, v.y, v.z, v.w};
#pragma unroll
        for (int q = 0; q < 4; q++) {
            float o[4]; f8d4(b4[q], o);
            int k = cb + q * 4;
            rowsT[(k + 0) * 36 + r] = o[0];
            rowsT[(k + 1) * 36 + r] = o[1];
            rowsT[(k + 2) * 36 + r] = o[2];
            rowsT[(k + 3) * 36 + r] = o[3];
        }
    }
    __syncthreads();
    int cg = t & 31, rg = t >> 5;
    int c0 = cg * 4, r0 = rg * 4;
    float acc[4][4] = {};
#pragma unroll 4
    for (int k = 0; k < 128; k++) {
        float4 a = *(const float4*)&rowsT[k * 36 + r0];
        ushort4 wv = *(const ushort4*)&wl[k * 128 + c0];
        float w0 = bfu(wv.x), w1 = bfu(wv.y), w2 = bfu(wv.z), w3 = bfu(wv.w);
        acc[0][0] += a.x * w0; acc[0][1] += a.x * w1; acc[0][2] += a.x * w2; acc[0][3] += a.x * w3;
        acc[1][0] += a.y * w0; acc[1][1] += a.y * w1; acc[1][2] += a.y * w2; acc[1][3] += a.y * w3;
        acc[2][0] += a.z * w0; acc[2][1] += a.z * w1; acc[2][2] += a.z * w2; acc[2][3] += a.z * w3;
        acc[3][0] += a.w * w0; acc[3][1] += a.w * w1; acc[3][2] += a.w * w2; acc[3][3] += a.w * w3;
    }
#pragma unroll
    for (int i = 0; i < 4; i++) {
        unsigned p = (unsigned)f8e2(acc[i][0], acc[i][1]) |
                     ((unsigned)f8e2(acc[i][2], acc[i][3]) << 16);
        *(unsigned*)(O + (size_t)(n0 + r0 + i) * 128 + c0) = p;
    }
}

// ---------------- GEMM 128x64: O = A(fp8) @ W3(bf16 LDS), fp8 out ------------
__global__ __launch_bounds__(256) void k_xform64(const unsigned char* __restrict__ A,
                                                 const unsigned short* __restrict__ Wb,
                                                 unsigned char* __restrict__ O) {
    __shared__ float rowsT[128 * 68];          // [k][r], 34.8 KB
    __shared__ unsigned short wl[128 * 64];    // 16 KB
    int t = threadIdx.x;
    int n0 = blockIdx.x * 64;
    {
        const uint4* wg = (const uint4*)Wb;
        uint4* wld = (uint4*)wl;
        for (int i = t; i < 1024; i += 256) wld[i] = wg[i];
    }
    {
        int r = t >> 2, cb = (t & 3) * 32;
        bool ok = (n0 + r) < NN;
        const uint4* ap = (const uint4*)(A + (size_t)(n0 + r) * 128 + cb);
#pragma unroll
        for (int h = 0; h < 2; h++) {
            uint4 v = ok ? ap[h] : make_uint4(0, 0, 0, 0);
            unsigned b4[4] = {v.x, v.y, v.z, v.w};
#pragma unroll
            for (int q = 0; q < 4; q++) {
                float o[4]; f8d4(b4[q], o);
                int k = cb + h * 16 + q * 4;
                rowsT[(k + 0) * 68 + r] = o[0];
                rowsT[(k + 1) * 68 + r] = o[1];
                rowsT[(k + 2) * 68 + r] = o[2];
                rowsT[(k + 3) * 68 + r] = o[3];
            }
        }
    }
    __syncthreads();
    int cg = t & 15, rg = t >> 4;
    int c0 = cg * 4, r0 = rg * 4;
    float acc[4][4] = {};
#pragma unroll 4
    for (int k = 0; k < 128; k++) {
        float4 a = *(const float4*)&rowsT[k * 68 + r0];
        ushort4 wv = *(const ushort4*)&wl[k * 64 + c0];
        float w0 = bfu(wv.x), w1 = bfu(wv.y), w2 = bfu(wv.z), w3 = bfu(wv.w);
        acc[0][0] += a.x * w0; acc[0][1] += a.x * w1; acc[0][2] += a.x * w2; acc[0][3] += a.x * w3;
        acc[1][0] += a.y * w0; acc[1][1] += a.y * w1; acc[1][2] += a.y * w2; acc[1][3] += a.y * w3;
        acc[2][0] += a.z * w0; acc[2][1] += a.z * w1; acc[2][2] += a.z * w2; acc[2][3] += a.z * w3;
        acc[3][0] += a.w * w0; acc[3][1] += a.w * w1; acc[3][2] += a.w * w2; acc[3][3] += a.w * w3;
    }
#pragma unroll
    for (int i = 0; i < 4; i++) {
        int n = n0 + r0 + i;
        if (n < NN) {
            unsigned p = (unsigned)f8e2(acc[i][0], acc[i][1]) |
                         ((unsigned)f8e2(acc[i][2], acc[i][3]) << 16);
            *(unsigned*)(O + (size_t)n * 64 + c0) = p;
        }
    }
}

// ---------------- agg, F=128: H = relu?(Anorm @ T + b), fp8 -> fp8 -----------
template <bool RELU>
__global__ __launch_bounds__(256) void k_agg128(const unsigned char* __restrict__ T,
                                                const int* __restrict__ rowptr,
                                                const int* __restrict__ csr,
                                                const float* __restrict__ dis,
                                                const float* __restrict__ bias,
                                                unsigned char* __restrict__ H) {
    int n = blockIdx.x * 4 + (threadIdx.x >> 6);
    int lane = threadIdx.x & 63;
    float dn = dis[n];
    int s0 = rowptr[n], s1 = rowptr[n + 1];
    s0 = min(max(s0, 0), NE); s1 = min(max(s1, s0), NE);
    unsigned short rself = *(const unsigned short*)(T + (size_t)n * 128 + lane * 2);
    float sx, sy; f8d2(rself, sx, sy);
    float dnn = dn * dn;
    float a0 = sx * dnn + bias[2 * lane];
    float a1 = sy * dnn + bias[2 * lane + 1];
    float b0 = 0, b1 = 0, c0 = 0, c1 = 0, d0 = 0, d1 = 0;
    for (int base = s0; base < s1; base += 64) {
        int m = min(64, s1 - base);
        int idx = 0; float wv = 0.0f;
        if (lane < m) {
            int ss = csr[base + lane];
            ss = min(max(ss, 0), NN - 1);
            idx = ss; wv = dis[ss] * dn;
        }
        unsigned wbits = __float_as_uint(wv);
        int j = 0;
        for (; j + 4 <= m; j += 4) {
            int sa = __builtin_amdgcn_readlane(idx, j);
            int sb = __builtin_amdgcn_readlane(idx, j + 1);
            int sc = __builtin_amdgcn_readlane(idx, j + 2);
            int sd = __builtin_amdgcn_readlane(idx, j + 3);
            float wa = __uint_as_float(__builtin_amdgcn_readlane(wbits, j));
            float wb = __uint_as_float(__builtin_amdgcn_readlane(wbits, j + 1));
            float wc = __uint_as_float(__builtin_amdgcn_readlane(wbits, j + 2));
            float wd = __uint_as_float(__builtin_amdgcn_readlane(wbits, j + 3));
            unsigned short ra = *(const unsigned short*)(T + (size_t)sa * 128 + lane * 2);
            unsigned short rb = *(const unsigned short*)(T + (size_t)sb * 128 + lane * 2);
            unsigned short rc = *(const unsigned short*)(T + (size_t)sc * 128 + lane * 2);
            unsigned short rd = *(const unsigned short*)(T + (size_t)sd * 128 + lane * 2);
            float x0, x1;
            f8d2(ra, x0, x1); a0 += x0 * wa; a1 += x1 * wa;
            f8d2(rb, x0, x1); b0 += x0 * wb; b1 += x1 * wb;
            f8d2(rc, x0, x1); c0 += x0 * wc; c1 += x1 * wc;
            f8d2(rd, x0, x1); d0 += x0 * wd; d1 += x1 * wd;
        }
        for (; j < m; j++) {
            int sa = __builtin_amdgcn_readlane(idx, j);
            float wa = __uint_as_float(__builtin_amdgcn_readlane(wbits, j));
            unsigned short ra = *(const unsigned short*)(T + (size_t)sa * 128 + lane * 2);
            float x0, x1; f8d2(ra, x0, x1);
            a0 += x0 * wa; a1 += x1 * wa;
        }
    }
    a0 += b0 + c0 + d0; a1 += b1 + c1 + d1;
    if (RELU) { a0 = fmaxf(a0, 0.0f); a1 = fmaxf(a1, 0.0f); }
    *(unsigned short*)(H + (size_t)n * 128 + lane * 2) = f8e2(a0, a1);
}

// ---------------- agg, F=64 final: h3 = Anorm @ T3 + b3 -> bf16 --------------
__global__ __launch_bounds__(256) void k_agg64(const unsigned char* __restrict__ T,
                                               const int* __restrict__ rowptr,
                                               const int* __restrict__ csr,
                                               const float* __restrict__ dis,
                                               const float* __restrict__ bias,
                                               unsigned short* __restrict__ Hb) {
    int n = blockIdx.x * 4 + (threadIdx.x >> 6);
    int lane = threadIdx.x & 63;
    float dn = dis[n];
    int s0 = rowptr[n], s1 = rowptr[n + 1];
    s0 = min(max(s0, 0), NE); s1 = min(max(s1, s0), NE);
    float a0 = f8d1(T[(size_t)n * 64 + lane]) * (dn * dn) + bias[lane];
    float b0 = 0, c0 = 0, d0 = 0;
    for (int base = s0; base < s1; base += 64) {
        int m = min(64, s1 - base);
        int idx = 0; float wv = 0.0f;
        if (lane < m) {
            int ss = csr[base + lane];
            ss = min(max(ss, 0), NN - 1);
            idx = ss; wv = dis[ss] * dn;
        }
        unsigned wbits = __float_as_uint(wv);
        int j = 0;
        for (; j + 4 <= m; j += 4) {
            int sa = __builtin_amdgcn_readlane(idx, j);
            int sb = __builtin_amdgcn_readlane(idx, j + 1);
            int sc = __builtin_amdgcn_readlane(idx, j + 2);
            int sd = __builtin_amdgcn_readlane(idx, j + 3);
            float wa = __uint_as_float(__builtin_amdgcn_readlane(wbits, j));
            float wb = __uint_as_float(__builtin_amdgcn_readlane(wbits, j + 1));
            float wc = __uint_as_float(__builtin_amdgcn_readlane(wbits, j + 2));
            float wd = __uint_as_float(__builtin_amdgcn_readlane(wbits, j + 3));
            unsigned ra = T[(size_t)sa * 64 + lane];
            unsigned rb = T[(size_t)sb * 64 + lane];
            unsigned rc = T[(size_t)sc * 64 + lane];
            unsigned rd = T[(size_t)sd * 64 + lane];
            a0 += f8d1(ra) * wa;
            b0 += f8d1(rb) * wb;
            c0 += f8d1(rc) * wc;
            d0 += f8d1(rd) * wd;
        }
        for (; j < m; j++) {
            int sa = __builtin_amdgcn_readlane(idx, j);
            float wa = __uint_as_float(__builtin_amdgcn_readlane(wbits, j));
            a0 += f8d1(T[(size_t)sa * 64 + lane]) * wa;
        }
    }
    a0 += b0 + c0 + d0;
    Hb[(size_t)n * 64 + lane] = __bfloat16_as_ushort(__float2bfloat16(a0));
}

// ---------------- attention pooling on Hb (bf16-as-ushort) ----------------
__global__ void k_colsum(const unsigned short* __restrict__ h3, float* __restrict__ colsum) {
    int lane = threadIdx.x & 63;
    int wave = (blockIdx.x * blockDim.x + threadIdx.x) >> 6;
    int nw = (gridDim.x * blockDim.x) >> 6;
    float acc = 0.0f;
    for (int n = wave; n < NN; n += nw) acc += bfu(h3[(size_t)n * 64 + lane]);
    __shared__ float sd[256];
    sd[threadIdx.x] = acc; __syncthreads();
    if (threadIdx.x < 64)
        atomicAdd(&colsum[threadIdx.x],
                  sd[threadIdx.x] + sd[threadIdx.x + 64] + sd[threadIdx.x + 128] + sd[threadIdx.x + 192]);
}

__global__ void k_ctx(const float* __restrict__ colsum, const float* __restrict__ Wa,
                      float* __restrict__ ctx) {
    __shared__ float ms[64];
    int j = threadIdx.x;
    ms[j] = colsum[j] * (1.0f / NN);
    __syncthreads();
    float s = 0.0f;
#pragma unroll
    for (int k = 0; k < 64; k++) s += ms[k] * Wa[k * 64 + j];
    ctx[j] = tanhf(s);
}

__global__ void k_pool(const unsigned short* __restrict__ h3, const float* __restrict__ ctx,
                       float* __restrict__ pooled) {
    int lane = threadIdx.x & 63;
    int wave = (blockIdx.x * blockDim.x + threadIdx.x) >> 6;
    int nw = (gridDim.x * blockDim.x) >> 6;
    float c = ctx[lane];
    float acc = 0.0f;
    for (int n = wave; n < NN; n += nw) {
        float v = bfu(h3[(size_t)n * 64 + lane]);
        float p = v * c;
#pragma unroll
        for (int m = 32; m > 0; m >>= 1) p += __shfl_xor(p, m, 64);
        float score = 1.0f / (1.0f + expf(-p));
        acc += score * v;
    }
    __shared__ float sd[256];
    sd[threadIdx.x] = acc; __syncthreads();
    if (threadIdx.x < 64)
        atomicAdd(&pooled[threadIdx.x],
                  sd[threadIdx.x] + sd[threadIdx.x + 64] + sd[threadIdx.x + 128] + sd[threadIdx.x + 192]);
}

// ---------------- final output write ----------------
__global__ void k_out(const unsigned short* __restrict__ h3, const float* __restrict__ pooled,
                      void* __restrict__ out, const int* __restrict__ flags) {
    long long i = (long long)blockIdx.x * blockDim.x + threadIdx.x;
    if (i >= 6400064LL) return;
    float v = (i < 6400000LL) ? bfu(h3[i]) : pooled[i - 6400000LL];
    if (flags[0]) ((float*)out)[i] = v;
    else          ((unsigned short*)out)[i] = __bfloat16_as_ushort(__float2bfloat16(v));
}

// ---------------- workspace layout (~21.5 MB) ----------------
static constexpr size_t AL(size_t x) { return (x + 255) & ~size_t(255); }
static constexpr size_t OFF_FLAGS  = 0;
static constexpr size_t OFF_RAW    = OFF_FLAGS + 256;
static constexpr size_t OFF_COUNTS = OFF_RAW + 256;
static constexpr size_t OFF_CURSOR = OFF_COUNTS + AL(NN * 4);
static constexpr size_t OFF_ROWPTR = OFF_CURSOR + AL(NN * 4);
static constexpr size_t OFF_BSUM   = OFF_ROWPTR + AL((NN + 1) * 4);
static constexpr size_t OFF_BOFF   = OFF_BSUM + AL(SCAN_NB * 4);
static constexpr size_t OFF_CSR    = OFF_BOFF + AL(SCAN_NB * 4);
static constexpr size_t OFF_DIS    = OFF_CSR + AL((size_t)NE * 4);
static constexpr size_t OFF_P      = OFF_DIS + AL(NN * 4);               // NN*128 fp8 / NN*64 bf16
static constexpr size_t OFF_W1B    = OFF_P + AL((size_t)NN * 128);
static constexpr size_t OFF_W2B    = OFF_W1B + AL(16384 * 2);
static constexpr size_t OFF_W3B    = OFF_W2B + AL(16384 * 2);
static constexpr size_t OFF_B1F    = OFF_W3B + AL(8192 * 2);
static constexpr size_t OFF_B2F    = OFF_B1F + AL(128 * 4);
static constexpr size_t OFF_B3F    = OFF_B2F + AL(128 * 4);
static constexpr size_t OFF_WAF    = OFF_B3F + AL(64 * 4);
static constexpr size_t OFF_COLSUM = OFF_WAF + AL(4096 * 4);
static constexpr size_t OFF_POOLED = OFF_COLSUM + AL(64 * 4);
static constexpr size_t OFF_CTX    = OFF_POOLED + AL(64 * 4);

extern "C" void kernel_launch(void* const* d_in, const int* in_sizes, int n_in,
                              void* d_out, int out_size, void* d_ws, size_t ws_size,
                              hipStream_t stream) {
    const int* ei = (const int*)d_in[0];
    const void* x  = d_in[1];
    const void* W1 = d_in[2];
    const void* b1 = d_in[3];
    const void* W2 = d_in[4];
    const void* b2 = d_in[5];
    const void* W3 = d_in[6];
    const void* b3 = d_in[7];
    const void* Wa = d_in[8];

    char* ws = (char*)d_ws;
    int*   flags  = (int*)(ws + OFF_FLAGS);
    int*   raw    = (int*)(ws + OFF_RAW);
    int*   counts = (int*)(ws + OFF_COUNTS);
    int*   cursor = (int*)(ws + OFF_CURSOR);
    int*   rowptr = (int*)(ws + OFF_ROWPTR);
    int*   bsum   = (int*)(ws + OFF_BSUM);
    int*   boff   = (int*)(ws + OFF_BOFF);
    int*   csr    = (int*)(ws + OFF_CSR);
    float* dis    = (float*)(ws + OFF_DIS);
    unsigned char*  P   = (unsigned char*)(ws + OFF_P);
    unsigned short* Hb  = (unsigned short*)(ws + OFF_P);   // reuse as bf16 h3
    unsigned short* W1b = (unsigned short*)(ws + OFF_W1B);
    unsigned short* W2b = (unsigned short*)(ws + OFF_W2B);
    unsigned short* W3b = (unsigned short*)(ws + OFF_W3B);
    float* b1f    = (float*)(ws + OFF_B1F);
    float* b2f    = (float*)(ws + OFF_B2F);
    float* b3f    = (float*)(ws + OFF_B3F);
    float* Waf    = (float*)(ws + OFF_WAF);
    float* colsum = (float*)(ws + OFF_COLSUM);
    float* pooled = (float*)(ws + OFF_POOLED);
    float* ctx    = (float*)(ws + OFF_CTX);

    unsigned char* Q = (unsigned char*)d_out;   // d_out doubles as T-scratch (12.8 MB)

    hipMemsetAsync(raw, 0, 256, stream);
    hipMemsetAsync(counts, 0, NN * 4, stream);
    hipMemsetAsync(cursor, 0, NN * 4, stream);
    hipMemsetAsync(colsum, 0, 64 * 4, stream);
    hipMemsetAsync(pooled, 0, 64 * 4, stream);

    k_probe1<<<256, 256, 0, stream>>>((const unsigned short*)x, ei, raw);
    k_probe2<<<1, 64, 0, stream>>>(raw, flags);
    cvt_params<<<64, 256, 0, stream>>>(W1, b1, W2, b2, W3, b3, Wa,
                                       W1b, W2b, W3b, b1f, b2f, b3f, Waf, flags);

    k_count<<<(NE + 255) / 256, 256, 0, stream>>>(ei, counts, flags);
    k_dis<<<(NN + 255) / 256, 256, 0, stream>>>(counts, dis);
    k_scan1<<<SCAN_NB, SCAN_T, 0, stream>>>(counts, bsum);
    k_scan2<<<1, 64, 0, stream>>>(bsum, boff, rowptr);
    k_scan3<<<SCAN_NB, SCAN_T, 0, stream>>>(counts, boff, rowptr);
    k_place<<<(NE + 255) / 256, 256, 0, stream>>>(ei, rowptr, cursor, csr, flags);

    // x -> fp8 P
    k_cvtx<<<(NN * 128 / 4 + 255) / 256, 256, 0, stream>>>(x, P, flags);

    // L1: T = P@W1 (Q) ; P = relu(Anorm@T + b1)
    k_xform128<<<NN / 32, 256, 0, stream>>>(P, W1b, Q);
    k_agg128<true><<<NN / 4, 256, 0, stream>>>(Q, rowptr, csr, dis, b1f, P);
    // L2
    k_xform128<<<NN / 32, 256, 0, stream>>>(P, W2b, Q);
    k_agg128<true><<<NN / 4, 256, 0, stream>>>(Q, rowptr, csr, dis, b2f, P);
    // L3: T3 = P@W3 (Q, 64 cols) ; Hb = Anorm@T3 + b3 (bf16, overwrites P)
    k_xform64<<<(NN + 63) / 64, 256, 0, stream>>>(P, W3b, Q);
    k_agg64<<<NN / 4, 256, 0, stream>>>(Q, rowptr, csr, dis, b3f, Hb);

    // attention pooling
    k_colsum<<<256, 256, 0, stream>>>(Hb, colsum);
    k_ctx<<<1, 64, 0, stream>>>(colsum, Waf, ctx);
    k_pool<<<256, 256, 0, stream>>>(Hb, ctx, pooled);

    // final output
    k_out<<<(6400064 + 255) / 256, 256, 0, stream>>>(Hb, pooled, d_out, flags);
}

// Round 6
// 641.067 us; speedup vs baseline: 2.4569x; 1.0536x over previous
//
#include <hip/hip_runtime.h>
#include <hip/hip_bf16.h>

#define NN 100000
#define NE 1600000
#define NR 100032            // NN rounded to 64-row blocks (table alloc rows)
#define NBUCK 3125           // NN / 32
#define SCAN_T 256
#define SCAN_E 1024
#define SCAN_NB ((NN + SCAN_E - 1) / SCAN_E)   // 98

#if defined(__has_builtin)
#  if __has_builtin(__builtin_amdgcn_cvt_pk_f32_fp8) && \
      __has_builtin(__builtin_amdgcn_cvt_pk_fp8_f32) && \
      __has_builtin(__builtin_amdgcn_cvt_f32_fp8)
#    define HWF8 1
#  endif
#endif

typedef float f32x2 __attribute__((ext_vector_type(2)));
typedef float f32x4 __attribute__((ext_vector_type(4)));
typedef short bf16x8 __attribute__((ext_vector_type(8)));

static __device__ __forceinline__ float bf2f(__hip_bfloat16 v) { return __bfloat162float(v); }
static __device__ __forceinline__ float bfu(unsigned short w) {
    return __uint_as_float((unsigned)w << 16);
}

// ---------------- fp8 e4m3 software codec (fallback, validated r3/r4) ---------
static __device__ __forceinline__ float f8d_sw(unsigned b) {
    unsigned e = (b >> 3) & 15u, m = b & 7u;
    float mag;
    if (e == 0) mag = (float)m * 0.001953125f;
    else        mag = __uint_as_float(((e + 120u) << 23) | (m << 20));
    return (b & 0x80u) ? -mag : mag;
}
static __device__ __forceinline__ unsigned char f8e_sw(float x) {
    unsigned u = __float_as_uint(x);
    unsigned s = (u >> 31) << 7;
    unsigned au = u & 0x7fffffffu;
    if (au >= 0x43E00000u) return (unsigned char)(s | 0x7Eu);
    if (au <  0x3A800000u) return (unsigned char)s;
    if (au <  0x3C800000u) {
        float a = __uint_as_float(au);
        int m = (int)rintf(a * 512.0f);
        if (m >= 8) return (unsigned char)(s | 0x08u);
        return (unsigned char)(s | (unsigned)m);
    }
    au += 0x80000u;
    if (au >= 0x43E00000u) return (unsigned char)(s | 0x7Eu);
    unsigned e = (au >> 23) - 120u;
    unsigned m = (au >> 20) & 7u;
    return (unsigned char)(s | (e << 3) | m);
}

// ---------------- fp8 helpers (HW if available) ----------------
static __device__ __forceinline__ float f8d1(unsigned b) {
#ifdef HWF8
    return __builtin_amdgcn_cvt_f32_fp8((int)b, 0);
#else
    return f8d_sw(b);
#endif
}
static __device__ __forceinline__ void f8d2(unsigned short v, float& x0, float& x1) {
#ifdef HWF8
    f32x2 r = __builtin_amdgcn_cvt_pk_f32_fp8((int)(unsigned)v, false);
    x0 = r.x; x1 = r.y;
#else
    x0 = f8d_sw(v & 255u); x1 = f8d_sw(v >> 8);
#endif
}
static __device__ __forceinline__ void f8d4(unsigned u, float* o) {
#ifdef HWF8
    f32x2 lo = __builtin_amdgcn_cvt_pk_f32_fp8((int)u, false);
    f32x2 hi = __builtin_amdgcn_cvt_pk_f32_fp8((int)u, true);
    o[0] = lo.x; o[1] = lo.y; o[2] = hi.x; o[3] = hi.y;
#else
    o[0] = f8d_sw(u & 255u); o[1] = f8d_sw((u >> 8) & 255u);
    o[2] = f8d_sw((u >> 16) & 255u); o[3] = f8d_sw(u >> 24);
#endif
}
static __device__ __forceinline__ unsigned short f8e2(float a, float b) {
#ifdef HWF8
    float ca = fminf(fmaxf(a, -448.0f), 448.0f);
    float cb = fminf(fmaxf(b, -448.0f), 448.0f);
    int p = __builtin_amdgcn_cvt_pk_fp8_f32(ca, cb, 0, false);
    return (unsigned short)(p & 0xFFFF);
#else
    return (unsigned short)f8e_sw(a) | ((unsigned short)f8e_sw(b) << 8);
#endif
}
static __device__ __forceinline__ unsigned char f8e1(float a) {
    return (unsigned char)(f8e2(a, 0.0f) & 0xFF);
}
// f32 -> bf16 bits by truncation (EXACT for values that came from fp8 e4m3)
static __device__ __forceinline__ unsigned bfpack(float lo, float hi) {
    return (__float_as_uint(lo) >> 16) | (__float_as_uint(hi) & 0xFFFF0000u);
}

// ---------------- dtype probes (parallel) ----------------
__global__ void k_probe1(const unsigned short* __restrict__ xw,
                         const int* __restrict__ ei, int* __restrict__ raw) {
    int i = blockIdx.x * 256 + threadIdx.x;    // 65536 probes
    int nan = ((xw[i] & 0x7F80u) == 0x7F80u) ? 1 : 0;
    int odd = (ei[2 * i + 1] != 0) ? 1 : 0;
    unsigned long long bn = __ballot(nan);
    unsigned long long bo = __ballot(odd);
    if ((threadIdx.x & 63) == 0) {
        if (bn) atomicAdd(&raw[0], __popcll(bn));
        if (bo) atomicAdd(&raw[1], __popcll(bo));
    }
}
__global__ void k_probe2(const int* __restrict__ raw, int* __restrict__ flags) {
    if (threadIdx.x == 0) {
        flags[0] = (raw[0] > 0) ? 1 : 0;   // x/weights are f32
        flags[1] = (raw[1] == 0) ? 1 : 0;  // edge_index is int64
    }
}

static __device__ __forceinline__ int e_src(const int* ei, int e, int f64) {
    int v = f64 ? ei[2 * e] : ei[e];
    return min(max(v, 0), NN - 1);
}
static __device__ __forceinline__ int e_dst(const int* ei, int e, int f64) {
    int v = f64 ? ei[2 * (NE + e)] : ei[NE + e];
    return min(max(v, 0), NN - 1);
}
static __device__ __forceinline__ float ldx(const void* p, long long i, int f32) {
    return f32 ? ((const float*)p)[i] : bf2f(((const __hip_bfloat16*)p)[i]);
}

// ------------- parameter conversion: W -> bf16 in MFMA-frag order -------------
// frag order for COLS=128: idx i: j=i&7, l=(i>>3)&63, c=(i>>9)&7, kc=i>>12;
//   k=kc*32+((l>>4))*8+j, f=c*16+(l&15); value = W[k*COLS+f].
__global__ void cvt_params(const void* W1, const void* b1, const void* W2, const void* b2,
                           const void* W3, const void* b3, const void* Wa,
                           unsigned short* W1b, unsigned short* W2b, unsigned short* W3b,
                           float* b1f, float* b2f, float* b3f, float* Waf,
                           const int* flags) {
    int i = blockIdx.x * blockDim.x + threadIdx.x;
    int f = flags[0];
    if (i < 16384) {
        int j = i & 7, l = (i >> 3) & 63, c = (i >> 9) & 7, kc = i >> 12;
        int k = kc * 32 + ((l >> 4)) * 8 + j;
        int col = c * 16 + (l & 15);
        W1b[i] = __bfloat16_as_ushort(__float2bfloat16(ldx(W1, k * 128 + col, f)));
        W2b[i] = __bfloat16_as_ushort(__float2bfloat16(ldx(W2, k * 128 + col, f)));
    }
    if (i < 8192) {
        int j = i & 7, l = (i >> 3) & 63, c = (i >> 9) & 3, kc = i >> 11;
        int k = kc * 32 + ((l >> 4)) * 8 + j;
        int col = c * 16 + (l & 15);
        W3b[i] = __bfloat16_as_ushort(__float2bfloat16(ldx(W3, k * 64 + col, f)));
    }
    if (i < 4096)  Waf[i] = ldx(Wa, i, f);
    if (i < 128)   { b1f[i] = ldx(b1, i, f); b2f[i] = ldx(b2, i, f); }
    if (i < 64)    b3f[i] = ldx(b3, i, f);
}

// ---------------- x -> fp8 table P ----------------
__global__ void k_cvtx(const void* __restrict__ x, unsigned char* __restrict__ P,
                       const int* __restrict__ flags) {
    int i = blockIdx.x * blockDim.x + threadIdx.x;      // one uint (4 elems) per thread
    if (i >= (NN * 128) / 4) return;
    unsigned pk;
    if (flags[0]) {
        float4 v = ((const float4*)x)[i];
        pk = (unsigned)f8e2(v.x, v.y) | ((unsigned)f8e2(v.z, v.w) << 16);
    } else {
        ushort4 v = ((const ushort4*)x)[i];
        pk = (unsigned)f8e2(bfu(v.x), bfu(v.y)) | ((unsigned)f8e2(bfu(v.z), bfu(v.w)) << 16);
    }
    ((unsigned*)P)[i] = pk;
}

// ---------------- degree count + dis ----------------
__global__ void k_count(const int* __restrict__ ei, int* __restrict__ counts,
                        const int* __restrict__ flags) {
    int e = blockIdx.x * blockDim.x + threadIdx.x;
    if (e < NE) atomicAdd(&counts[e_dst(ei, e, flags[1])], 1);
}

__global__ void k_dis(const int* __restrict__ counts, float* __restrict__ dis) {
    int n = blockIdx.x * blockDim.x + threadIdx.x;
    if (n < NN) dis[n] = rsqrtf((float)counts[n] + 1.0f);
}

// ---------------- exclusive scan -> rowptr ----------------
__global__ void k_scan1(const int* __restrict__ counts, int* __restrict__ bsum) {
    __shared__ int sd[SCAN_T];
    int b = blockIdx.x, t = threadIdx.x;
    int base = b * SCAN_E + t * 4;
    int s = 0;
#pragma unroll
    for (int i = 0; i < 4; i++) { int idx = base + i; if (idx < NN) s += counts[idx]; }
    sd[t] = s; __syncthreads();
    for (int o = SCAN_T / 2; o > 0; o >>= 1) {
        if (t < o) sd[t] += sd[t + o];
        __syncthreads();
    }
    if (t == 0) bsum[b] = sd[0];
}

__global__ void k_scan2(const int* __restrict__ bsum, int* __restrict__ boff,
                        int* __restrict__ rowptr) {
    if (threadIdx.x == 0 && blockIdx.x == 0) {
        int run = 0;
        for (int b = 0; b < SCAN_NB; b++) { boff[b] = run; run += bsum[b]; }
        rowptr[NN] = run;
    }
}

__global__ void k_scan3(const int* __restrict__ counts, const int* __restrict__ boff,
                        int* __restrict__ rowptr) {
    __shared__ int sd[SCAN_T];
    int b = blockIdx.x, t = threadIdx.x;
    int base = b * SCAN_E + t * 4;
    int v[4]; int s = 0;
#pragma unroll
    for (int i = 0; i < 4; i++) { int idx = base + i; v[i] = (idx < NN) ? counts[idx] : 0; s += v[i]; }
    sd[t] = s; __syncthreads();
    for (int o = 1; o < SCAN_T; o <<= 1) {
        int add = (t >= o) ? sd[t - o] : 0;
        __syncthreads();
        sd[t] += add;
        __syncthreads();
    }
    int run = sd[t] - s + boff[b];
#pragma unroll
    for (int i = 0; i < 4; i++) {
        int idx = base + i;
        if (idx < NN) { rowptr[idx] = run; run += v[i]; }
    }
}

// -------- CSR place, phase A: scatter packed (src,dst_lo) into bucket regions --
__global__ void k_placeA(const int* __restrict__ ei, const int* __restrict__ rowptr,
                         int* __restrict__ bcur, int* __restrict__ scratch,
                         const int* __restrict__ flags) {
    int e = blockIdx.x * blockDim.x + threadIdx.x;
    if (e < NE) {
        int f64 = flags[1];
        int d = e_dst(ei, e, f64);
        int s = e_src(ei, e, f64);
        int b = d >> 5;
        int pos = atomicAdd(&bcur[b], 1);
        int base = rowptr[b << 5];
        int p = min(base + pos, NE - 1);
        scratch[p] = s | ((d & 31) << 17);
    }
}

// -------- CSR place, phase B: per-bucket local placement (contiguous window) ---
__global__ __launch_bounds__(256) void k_placeB(const int* __restrict__ scratch,
                                                const int* __restrict__ rowptr,
                                                int* __restrict__ csr) {
    __shared__ int cur[32];
    int b = blockIdx.x;
    int t = threadIdx.x;
    if (t < 32) cur[t] = rowptr[(b << 5) + t];
    __syncthreads();
    int start = rowptr[b << 5];
    int end = rowptr[(b << 5) + 32];
    for (int i = start + t; i < end; i += 256) {
        int v = scratch[i];
        int s = v & 0x1FFFF;
        int dlo = (v >> 17) & 31;
        int p = atomicAdd(&cur[dlo], 1);
        p = min(max(p, 0), NE - 1);
        csr[p] = s;
    }
}

// ------------- MFMA GEMM: O[NNxCOLS] = A(fp8,128) @ W(bf16 frag-order) --------
// block: 256 thr = 4 waves, 64 rows; wave w: rows n0+16w..+15, all COLS cols.
template <int NCT>    // NCT = COLS/16 (8 or 4)
__global__ __launch_bounds__(256) void k_xf_mfma(const unsigned char* __restrict__ A,
                                                 const unsigned short* __restrict__ Wf,
                                                 unsigned char* __restrict__ O) {
    __shared__ unsigned short wl[NCT * 4 * 64 * 8];    // frag-order W (NCT*4 KBx4)
    int t = threadIdx.x;
    int n0 = blockIdx.x * 64;
    {
        const uint4* wg = (const uint4*)Wf;
        uint4* wld = (uint4*)wl;
#pragma unroll
        for (int i = 0; i < NCT; i++) wld[i * 256 + t] = wg[i * 256 + t];
    }
    __syncthreads();
    int w = t >> 6, l = t & 63;
    int quad = l >> 4, m = l & 15;
    int arow = n0 + w * 16 + m;
    const unsigned char* ap = A + (size_t)arow * 128 + quad * 8;
    f32x4 acc[NCT];
#pragma unroll
    for (int c = 0; c < NCT; c++) acc[c] = (f32x4){0.0f, 0.0f, 0.0f, 0.0f};
#pragma unroll
    for (int kc = 0; kc < 4; kc++) {
        uint2 g = *(const uint2*)(ap + kc * 32);
        float o[8];
        f8d4(g.x, o); f8d4(g.y, o + 4);
        union { unsigned u[4]; bf16x8 v; } fr;
        fr.u[0] = bfpack(o[0], o[1]);
        fr.u[1] = bfpack(o[2], o[3]);
        fr.u[2] = bfpack(o[4], o[5]);
        fr.u[3] = bfpack(o[6], o[7]);
#pragma unroll
        for (int c = 0; c < NCT; c++) {
            bf16x8 bw = *(const bf16x8*)&wl[((kc * NCT + c) * 64 + l) * 8];
            acc[c] = __builtin_amdgcn_mfma_f32_16x16x32_bf16(fr.v, bw, acc[c], 0, 0, 0);
        }
    }
    int orow0 = n0 + w * 16 + quad * 4;
#pragma unroll
    for (int c = 0; c < NCT; c++) {
        int col = c * 16 + m;
#pragma unroll
        for (int r = 0; r < 4; r++) {
            int row = orow0 + r;
            if (row < NN) O[(size_t)row * (NCT * 16) + col] = f8e1(acc[c][r]);
        }
    }
}

// ---------------- agg, F=128: H = relu?(Anorm @ T + b), fp8 -> fp8 -----------
template <bool RELU>
__global__ __launch_bounds__(256) void k_agg128(const unsigned char* __restrict__ T,
                                                const int* __restrict__ rowptr,
                                                const int* __restrict__ csr,
                                                const float* __restrict__ dis,
                                                const float* __restrict__ bias,
                                                unsigned char* __restrict__ H) {
    int n = blockIdx.x * 4 + (threadIdx.x >> 6);
    int lane = threadIdx.x & 63;
    float dn = dis[n];
    int s0 = rowptr[n], s1 = rowptr[n + 1];
    s0 = min(max(s0, 0), NE); s1 = min(max(s1, s0), NE);
    unsigned short rself = *(const unsigned short*)(T + (size_t)n * 128 + lane * 2);
    float sx, sy; f8d2(rself, sx, sy);
    float dnn = dn * dn;
    float a0 = sx * dnn + bias[2 * lane];
    float a1 = sy * dnn + bias[2 * lane + 1];
    float b0 = 0, b1 = 0, c0 = 0, c1 = 0, d0 = 0, d1 = 0;
    for (int base = s0; base < s1; base += 64) {
        int m = min(64, s1 - base);
        int idx = 0; float wv = 0.0f;
        if (lane < m) {
            int ss = csr[base + lane];
            ss = min(max(ss, 0), NN - 1);
            idx = ss; wv = dis[ss] * dn;
        }
        unsigned wbits = __float_as_uint(wv);
        int j = 0;
        for (; j + 4 <= m; j += 4) {
            int sa = __builtin_amdgcn_readlane(idx, j);
            int sb = __builtin_amdgcn_readlane(idx, j + 1);
            int sc = __builtin_amdgcn_readlane(idx, j + 2);
            int sd = __builtin_amdgcn_readlane(idx, j + 3);
            float wa = __uint_as_float(__builtin_amdgcn_readlane(wbits, j));
            float wb = __uint_as_float(__builtin_amdgcn_readlane(wbits, j + 1));
            float wc = __uint_as_float(__builtin_amdgcn_readlane(wbits, j + 2));
            float wd = __uint_as_float(__builtin_amdgcn_readlane(wbits, j + 3));
            unsigned short ra = *(const unsigned short*)(T + (size_t)sa * 128 + lane * 2);
            unsigned short rb = *(const unsigned short*)(T + (size_t)sb * 128 + lane * 2);
            unsigned short rc = *(const unsigned short*)(T + (size_t)sc * 128 + lane * 2);
            unsigned short rd = *(const unsigned short*)(T + (size_t)sd * 128 + lane * 2);
            float x0, x1;
            f8d2(ra, x0, x1); a0 += x0 * wa; a1 += x1 * wa;
            f8d2(rb, x0, x1); b0 += x0 * wb; b1 += x1 * wb;
            f8d2(rc, x0, x1); c0 += x0 * wc; c1 += x1 * wc;
            f8d2(rd, x0, x1); d0 += x0 * wd; d1 += x1 * wd;
        }
        for (; j < m; j++) {
            int sa = __builtin_amdgcn_readlane(idx, j);
            float wa = __uint_as_float(__builtin_amdgcn_readlane(wbits, j));
            unsigned short ra = *(const unsigned short*)(T + (size_t)sa * 128 + lane * 2);
            float x0, x1; f8d2(ra, x0, x1);
            a0 += x0 * wa; a1 += x1 * wa;
        }
    }
    a0 += b0 + c0 + d0; a1 += b1 + c1 + d1;
    if (RELU) { a0 = fmaxf(a0, 0.0f); a1 = fmaxf(a1, 0.0f); }
    *(unsigned short*)(H + (size_t)n * 128 + lane * 2) = f8e2(a0, a1);
}

// ---------------- agg, F=64 final: h3 = Anorm @ T3 + b3 -> bf16 --------------
__global__ __launch_bounds__(256) void k_agg64(const unsigned char* __restrict__ T,
                                               const int* __restrict__ rowptr,
                                               const int* __restrict__ csr,
                                               const float* __restrict__ dis,
                                               const float* __restrict__ bias,
                                               unsigned short* __restrict__ Hb) {
    int n = blockIdx.x * 4 + (threadIdx.x >> 6);
    int lane = threadIdx.x & 63;
    float dn = dis[n];
    int s0 = rowptr[n], s1 = rowptr[n + 1];
    s0 = min(max(s0, 0), NE); s1 = min(max(s1, s0), NE);
    float a0 = f8d1(T[(size_t)n * 64 + lane]) * (dn * dn) + bias[lane];
    float b0 = 0, c0 = 0, d0 = 0;
    for (int base = s0; base < s1; base += 64) {
        int m = min(64, s1 - base);
        int idx = 0; float wv = 0.0f;
        if (lane < m) {
            int ss = csr[base + lane];
            ss = min(max(ss, 0), NN - 1);
            idx = ss; wv = dis[ss] * dn;
        }
        unsigned wbits = __float_as_uint(wv);
        int j = 0;
        for (; j + 4 <= m; j += 4) {
            int sa = __builtin_amdgcn_readlane(idx, j);
            int sb = __builtin_amdgcn_readlane(idx, j + 1);
            int sc = __builtin_amdgcn_readlane(idx, j + 2);
            int sd = __builtin_amdgcn_readlane(idx, j + 3);
            float wa = __uint_as_float(__builtin_amdgcn_readlane(wbits, j));
            float wb = __uint_as_float(__builtin_amdgcn_readlane(wbits, j + 1));
            float wc = __uint_as_float(__builtin_amdgcn_readlane(wbits, j + 2));
            float wd = __uint_as_float(__builtin_amdgcn_readlane(wbits, j + 3));
            unsigned ra = T[(size_t)sa * 64 + lane];
            unsigned rb = T[(size_t)sb * 64 + lane];
            unsigned rc = T[(size_t)sc * 64 + lane];
            unsigned rd = T[(size_t)sd * 64 + lane];
            a0 += f8d1(ra) * wa;
            b0 += f8d1(rb) * wb;
            c0 += f8d1(rc) * wc;
            d0 += f8d1(rd) * wd;
        }
        for (; j < m; j++) {
            int sa = __builtin_amdgcn_readlane(idx, j);
            float wa = __uint_as_float(__builtin_amdgcn_readlane(wbits, j));
            a0 += f8d1(T[(size_t)sa * 64 + lane]) * wa;
        }
    }
    a0 += b0 + c0 + d0;
    Hb[(size_t)n * 64 + lane] = __bfloat16_as_ushort(__float2bfloat16(a0));
}

// ---------------- attention pooling on Hb (bf16-as-ushort) ----------------
__global__ void k_colsum(const unsigned short* __restrict__ h3, float* __restrict__ colsum) {
    int lane = threadIdx.x & 63;
    int wave = (blockIdx.x * blockDim.x + threadIdx.x) >> 6;
    int nw = (gridDim.x * blockDim.x) >> 6;
    float acc = 0.0f;
    for (int n = wave; n < NN; n += nw) acc += bfu(h3[(size_t)n * 64 + lane]);
    __shared__ float sd[256];
    sd[threadIdx.x] = acc; __syncthreads();
    if (threadIdx.x < 64)
        atomicAdd(&colsum[threadIdx.x],
                  sd[threadIdx.x] + sd[threadIdx.x + 64] + sd[threadIdx.x + 128] + sd[threadIdx.x + 192]);
}

__global__ void k_ctx(const float* __restrict__ colsum, const float* __restrict__ Wa,
                      float* __restrict__ ctx) {
    __shared__ float ms[64];
    int j = threadIdx.x;
    ms[j] = colsum[j] * (1.0f / NN);
    __syncthreads();
    float s = 0.0f;
#pragma unroll
    for (int k = 0; k < 64; k++) s += ms[k] * Wa[k * 64 + j];
    ctx[j] = tanhf(s);
}

__global__ void k_pool(const unsigned short* __restrict__ h3, const float* __restrict__ ctx,
                       float* __restrict__ pooled) {
    int lane = threadIdx.x & 63;
    int wave = (blockIdx.x * blockDim.x + threadIdx.x) >> 6;
    int nw = (gridDim.x * blockDim.x) >> 6;
    float c = ctx[lane];
    float acc = 0.0f;
    for (int n = wave; n < NN; n += nw) {
        float v = bfu(h3[(size_t)n * 64 + lane]);
        float p = v * c;
#pragma unroll
        for (int m = 32; m > 0; m >>= 1) p += __shfl_xor(p, m, 64);
        float score = 1.0f / (1.0f + expf(-p));
        acc += score * v;
    }
    __shared__ float sd[256];
    sd[threadIdx.x] = acc; __syncthreads();
    if (threadIdx.x < 64)
        atomicAdd(&pooled[threadIdx.x],
                  sd[threadIdx.x] + sd[threadIdx.x + 64] + sd[threadIdx.x + 128] + sd[threadIdx.x + 192]);
}

// ---------------- final output write ----------------
__global__ void k_out(const unsigned short* __restrict__ h3, const float* __restrict__ pooled,
                      void* __restrict__ out, const int* __restrict__ flags) {
    long long i = (long long)blockIdx.x * blockDim.x + threadIdx.x;
    if (i >= 6400064LL) return;
    float v = (i < 6400000LL) ? bfu(h3[i]) : pooled[i - 6400000LL];
    if (flags[0]) ((float*)out)[i] = v;
    else          ((unsigned short*)out)[i] = __bfloat16_as_ushort(__float2bfloat16(v));
}

// ---------------- workspace layout (~21.5 MB) ----------------
static constexpr size_t AL(size_t x) { return (x + 255) & ~size_t(255); }
static constexpr size_t OFF_FLAGS  = 0;
static constexpr size_t OFF_RAW    = OFF_FLAGS + 256;
static constexpr size_t OFF_COUNTS = OFF_RAW + 256;
static constexpr size_t OFF_BCUR   = OFF_COUNTS + AL(NN * 4);
static constexpr size_t OFF_ROWPTR = OFF_BCUR + AL(NBUCK * 4);
static constexpr size_t OFF_BSUM   = OFF_ROWPTR + AL((NN + 1) * 4);
static constexpr size_t OFF_BOFF   = OFF_BSUM + AL(SCAN_NB * 4);
static constexpr size_t OFF_CSR    = OFF_BOFF + AL(SCAN_NB * 4);
static constexpr size_t OFF_DIS    = OFF_CSR + AL((size_t)NE * 4);
static constexpr size_t OFF_P      = OFF_DIS + AL(NN * 4);        // NR*128 fp8; also phase-A scratch; also bf16 h3
static constexpr size_t OFF_W1B    = OFF_P + AL((size_t)NR * 128);
static constexpr size_t OFF_W2B    = OFF_W1B + AL(16384 * 2);
static constexpr size_t OFF_W3B    = OFF_W2B + AL(16384 * 2);
static constexpr size_t OFF_B1F    = OFF_W3B + AL(8192 * 2);
static constexpr size_t OFF_B2F    = OFF_B1F + AL(128 * 4);
static constexpr size_t OFF_B3F    = OFF_B2F + AL(128 * 4);
static constexpr size_t OFF_WAF    = OFF_B3F + AL(64 * 4);
static constexpr size_t OFF_COLSUM = OFF_WAF + AL(4096 * 4);
static constexpr size_t OFF_POOLED = OFF_COLSUM + AL(64 * 4);
static constexpr size_t OFF_CTX    = OFF_POOLED + AL(64 * 4);

extern "C" void kernel_launch(void* const* d_in, const int* in_sizes, int n_in,
                              void* d_out, int out_size, void* d_ws, size_t ws_size,
                              hipStream_t stream) {
    const int* ei = (const int*)d_in[0];
    const void* x  = d_in[1];
    const void* W1 = d_in[2];
    const void* b1 = d_in[3];
    const void* W2 = d_in[4];
    const void* b2 = d_in[5];
    const void* W3 = d_in[6];
    const void* b3 = d_in[7];
    const void* Wa = d_in[8];

    char* ws = (char*)d_ws;
    int*   flags  = (int*)(ws + OFF_FLAGS);
    int*   raw    = (int*)(ws + OFF_RAW);
    int*   counts = (int*)(ws + OFF_COUNTS);
    int*   bcur   = (int*)(ws + OFF_BCUR);
    int*   rowptr = (int*)(ws + OFF_ROWPTR);
    int*   bsum   = (int*)(ws + OFF_BSUM);
    int*   boff   = (int*)(ws + OFF_BOFF);
    int*   csr    = (int*)(ws + OFF_CSR);
    float* dis    = (float*)(ws + OFF_DIS);
    unsigned char*  P    = (unsigned char*)(ws + OFF_P);
    int*            scrA = (int*)(ws + OFF_P);             // phase-A scratch (6.4 MB < 12.8)
    unsigned short* Hb   = (unsigned short*)(ws + OFF_P);  // bf16 h3 after L3
    unsigned short* W1b = (unsigned short*)(ws + OFF_W1B);
    unsigned short* W2b = (unsigned short*)(ws + OFF_W2B);
    unsigned short* W3b = (unsigned short*)(ws + OFF_W3B);
    float* b1f    = (float*)(ws + OFF_B1F);
    float* b2f    = (float*)(ws + OFF_B2F);
    float* b3f    = (float*)(ws + OFF_B3F);
    float* Waf    = (float*)(ws + OFF_WAF);
    float* colsum = (float*)(ws + OFF_COLSUM);
    float* pooled = (float*)(ws + OFF_POOLED);
    float* ctx    = (float*)(ws + OFF_CTX);

    unsigned char* Q = (unsigned char*)d_out;   // d_out doubles as T-scratch (12.8 MB)

    hipMemsetAsync(raw, 0, 256, stream);
    hipMemsetAsync(counts, 0, NN * 4, stream);
    hipMemsetAsync(bcur, 0, NBUCK * 4, stream);
    hipMemsetAsync(colsum, 0, 64 * 4, stream);
    hipMemsetAsync(pooled, 0, 64 * 4, stream);

    k_probe1<<<256, 256, 0, stream>>>((const unsigned short*)x, ei, raw);
    k_probe2<<<1, 64, 0, stream>>>(raw, flags);
    cvt_params<<<64, 256, 0, stream>>>(W1, b1, W2, b2, W3, b3, Wa,
                                       W1b, W2b, W3b, b1f, b2f, b3f, Waf, flags);

    k_count<<<(NE + 255) / 256, 256, 0, stream>>>(ei, counts, flags);
    k_dis<<<(NN + 255) / 256, 256, 0, stream>>>(counts, dis);
    k_scan1<<<SCAN_NB, SCAN_T, 0, stream>>>(counts, bsum);
    k_scan2<<<1, 64, 0, stream>>>(bsum, boff, rowptr);
    k_scan3<<<SCAN_NB, SCAN_T, 0, stream>>>(counts, boff, rowptr);

    // bucketed CSR build (phase-A scratch lives in P region, before k_cvtx)
    k_placeA<<<(NE + 255) / 256, 256, 0, stream>>>(ei, rowptr, bcur, scrA, flags);
    k_placeB<<<NBUCK, 256, 0, stream>>>(scrA, rowptr, csr);

    // x -> fp8 P (overwrites phase-A scratch)
    k_cvtx<<<(NN * 128 / 4 + 255) / 256, 256, 0, stream>>>(x, P, flags);

    // L1: T = P@W1 (Q, MFMA) ; P = relu(Anorm@T + b1)
    k_xf_mfma<8><<<NR / 64, 256, 0, stream>>>(P, W1b, Q);
    k_agg128<true><<<NN / 4, 256, 0, stream>>>(Q, rowptr, csr, dis, b1f, P);
    // L2
    k_xf_mfma<8><<<NR / 64, 256, 0, stream>>>(P, W2b, Q);
    k_agg128<true><<<NN / 4, 256, 0, stream>>>(Q, rowptr, csr, dis, b2f, P);
    // L3: T3 = P@W3 (Q, 64 cols) ; Hb = Anorm@T3 + b3 (bf16, overwrites P)
    k_xf_mfma<4><<<NR / 64, 256, 0, stream>>>(P, W3b, Q);
    k_agg64<<<NN / 4, 256, 0, stream>>>(Q, rowptr, csr, dis, b3f, Hb);

    // attention pooling
    k_colsum<<<256, 256, 0, stream>>>(Hb, colsum);
    k_ctx<<<1, 64, 0, stream>>>(colsum, Waf, ctx);
    k_pool<<<256, 256, 0, stream>>>(Hb, ctx, pooled);

    // final output
    k_out<<<(6400064 + 255) / 256, 256, 0, stream>>>(Hb, pooled, d_out, flags);
}

// Round 7
// 492.039 us; speedup vs baseline: 3.2010x; 1.3029x over previous
//
#include <hip/hip_runtime.h>
#include <hip/hip_bf16.h>

#define NN 100000
#define NE 1600000
#define NR 100032            // NN rounded to 64-row blocks (table alloc rows)
#define NB2 196              // coarse buckets = ceil(NN/512)
#define NBLK 391             // hist/scatter blocks = ceil(NE/4096)
#define EPB 4096             // edges per hist/scatter block

#if defined(__has_builtin)
#  if __has_builtin(__builtin_amdgcn_cvt_pk_f32_fp8) && \
      __has_builtin(__builtin_amdgcn_cvt_pk_fp8_f32) && \
      __has_builtin(__builtin_amdgcn_cvt_f32_fp8)
#    define HWF8 1
#  endif
#endif

typedef float f32x2 __attribute__((ext_vector_type(2)));
typedef float f32x4 __attribute__((ext_vector_type(4)));
typedef short bf16x8 __attribute__((ext_vector_type(8)));

static __device__ __forceinline__ float bf2f(__hip_bfloat16 v) { return __bfloat162float(v); }
static __device__ __forceinline__ float bfu(unsigned short w) {
    return __uint_as_float((unsigned)w << 16);
}

// ---------------- fp8 e4m3 software codec (fallback, validated r3/r4) ---------
static __device__ __forceinline__ float f8d_sw(unsigned b) {
    unsigned e = (b >> 3) & 15u, m = b & 7u;
    float mag;
    if (e == 0) mag = (float)m * 0.001953125f;
    else        mag = __uint_as_float(((e + 120u) << 23) | (m << 20));
    return (b & 0x80u) ? -mag : mag;
}
static __device__ __forceinline__ unsigned char f8e_sw(float x) {
    unsigned u = __float_as_uint(x);
    unsigned s = (u >> 31) << 7;
    unsigned au = u & 0x7fffffffu;
    if (au >= 0x43E00000u) return (unsigned char)(s | 0x7Eu);
    if (au <  0x3A800000u) return (unsigned char)s;
    if (au <  0x3C800000u) {
        float a = __uint_as_float(au);
        int m = (int)rintf(a * 512.0f);
        if (m >= 8) return (unsigned char)(s | 0x08u);
        return (unsigned char)(s | (unsigned)m);
    }
    au += 0x80000u;
    if (au >= 0x43E00000u) return (unsigned char)(s | 0x7Eu);
    unsigned e = (au >> 23) - 120u;
    unsigned m = (au >> 20) & 7u;
    return (unsigned char)(s | (e << 3) | m);
}

// ---------------- fp8 helpers (HW if available) ----------------
static __device__ __forceinline__ float f8d1(unsigned b) {
#ifdef HWF8
    return __builtin_amdgcn_cvt_f32_fp8((int)b, 0);
#else
    return f8d_sw(b);
#endif
}
static __device__ __forceinline__ void f8d2(unsigned short v, float& x0, float& x1) {
#ifdef HWF8
    f32x2 r = __builtin_amdgcn_cvt_pk_f32_fp8((int)(unsigned)v, false);
    x0 = r.x; x1 = r.y;
#else
    x0 = f8d_sw(v & 255u); x1 = f8d_sw(v >> 8);
#endif
}
static __device__ __forceinline__ void f8d4(unsigned u, float* o) {
#ifdef HWF8
    f32x2 lo = __builtin_amdgcn_cvt_pk_f32_fp8((int)u, false);
    f32x2 hi = __builtin_amdgcn_cvt_pk_f32_fp8((int)u, true);
    o[0] = lo.x; o[1] = lo.y; o[2] = hi.x; o[3] = hi.y;
#else
    o[0] = f8d_sw(u & 255u); o[1] = f8d_sw((u >> 8) & 255u);
    o[2] = f8d_sw((u >> 16) & 255u); o[3] = f8d_sw(u >> 24);
#endif
}
static __device__ __forceinline__ unsigned short f8e2(float a, float b) {
#ifdef HWF8
    float ca = fminf(fmaxf(a, -448.0f), 448.0f);
    float cb = fminf(fmaxf(b, -448.0f), 448.0f);
    int p = __builtin_amdgcn_cvt_pk_fp8_f32(ca, cb, 0, false);
    return (unsigned short)(p & 0xFFFF);
#else
    return (unsigned short)f8e_sw(a) | ((unsigned short)f8e_sw(b) << 8);
#endif
}
static __device__ __forceinline__ unsigned char f8e1(float a) {
    return (unsigned char)(f8e2(a, 0.0f) & 0xFF);
}
// f32 -> bf16 bits by truncation (EXACT for values that came from fp8 e4m3)
static __device__ __forceinline__ unsigned bfpack(float lo, float hi) {
    return (__float_as_uint(lo) >> 16) | (__float_as_uint(hi) & 0xFFFF0000u);
}

// ---------------- dtype probes (parallel) ----------------
__global__ void k_probe1(const unsigned short* __restrict__ xw,
                         const int* __restrict__ ei, int* __restrict__ raw) {
    int i = blockIdx.x * 256 + threadIdx.x;    // 65536 probes
    int nan = ((xw[i] & 0x7F80u) == 0x7F80u) ? 1 : 0;
    int odd = (ei[2 * i + 1] != 0) ? 1 : 0;
    unsigned long long bn = __ballot(nan);
    unsigned long long bo = __ballot(odd);
    if ((threadIdx.x & 63) == 0) {
        if (bn) atomicAdd(&raw[0], __popcll(bn));
        if (bo) atomicAdd(&raw[1], __popcll(bo));
    }
}
__global__ void k_probe2(const int* __restrict__ raw, int* __restrict__ flags) {
    if (threadIdx.x == 0) {
        flags[0] = (raw[0] > 0) ? 1 : 0;   // x/weights are f32
        flags[1] = (raw[1] == 0) ? 1 : 0;  // edge_index is int64
    }
}

static __device__ __forceinline__ int e_src(const int* ei, int e, int f64) {
    int v = f64 ? ei[2 * e] : ei[e];
    return min(max(v, 0), NN - 1);
}
static __device__ __forceinline__ int e_dst(const int* ei, int e, int f64) {
    int v = f64 ? ei[2 * (NE + e)] : ei[NE + e];
    return min(max(v, 0), NN - 1);
}
static __device__ __forceinline__ float ldx(const void* p, long long i, int f32) {
    return f32 ? ((const float*)p)[i] : bf2f(((const __hip_bfloat16*)p)[i]);
}

// ------------- parameter conversion: W -> bf16 in MFMA-frag order -------------
__global__ void cvt_params(const void* W1, const void* b1, const void* W2, const void* b2,
                           const void* W3, const void* b3, const void* Wa,
                           unsigned short* W1b, unsigned short* W2b, unsigned short* W3b,
                           float* b1f, float* b2f, float* b3f, float* Waf,
                           const int* flags) {
    int i = blockIdx.x * blockDim.x + threadIdx.x;
    int f = flags[0];
    if (i < 16384) {
        int j = i & 7, l = (i >> 3) & 63, c = (i >> 9) & 7, kc = i >> 12;
        int k = kc * 32 + ((l >> 4)) * 8 + j;
        int col = c * 16 + (l & 15);
        W1b[i] = __bfloat16_as_ushort(__float2bfloat16(ldx(W1, k * 128 + col, f)));
        W2b[i] = __bfloat16_as_ushort(__float2bfloat16(ldx(W2, k * 128 + col, f)));
    }
    if (i < 8192) {
        int j = i & 7, l = (i >> 3) & 63, c = (i >> 9) & 3, kc = i >> 11;
        int k = kc * 32 + ((l >> 4)) * 8 + j;
        int col = c * 16 + (l & 15);
        W3b[i] = __bfloat16_as_ushort(__float2bfloat16(ldx(W3, k * 64 + col, f)));
    }
    if (i < 4096)  Waf[i] = ldx(Wa, i, f);
    if (i < 128)   { b1f[i] = ldx(b1, i, f); b2f[i] = ldx(b2, i, f); }
    if (i < 64)    b3f[i] = ldx(b3, i, f);
}

// ---------------- x -> fp8 table P ----------------
__global__ void k_cvtx(const void* __restrict__ x, unsigned char* __restrict__ P,
                       const int* __restrict__ flags) {
    int i = blockIdx.x * blockDim.x + threadIdx.x;
    if (i >= (NN * 128) / 4) return;
    unsigned pk;
    if (flags[0]) {
        float4 v = ((const float4*)x)[i];
        pk = (unsigned)f8e2(v.x, v.y) | ((unsigned)f8e2(v.z, v.w) << 16);
    } else {
        ushort4 v = ((const ushort4*)x)[i];
        pk = (unsigned)f8e2(bfu(v.x), bfu(v.y)) | ((unsigned)f8e2(bfu(v.z), bfu(v.w)) << 16);
    }
    ((unsigned*)P)[i] = pk;
}

// ======== CSR build: atomic-free multisplit (r7) ========
// kA: per-block LDS histogram over 196 coarse buckets (dst>>9)
__global__ __launch_bounds__(256) void k_hist(const int* __restrict__ ei,
                                              int* __restrict__ ghist,
                                              const int* __restrict__ flags) {
    __shared__ int h[NB2];
    int blk = blockIdx.x, t = threadIdx.x;
    for (int i = t; i < NB2; i += 256) h[i] = 0;
    __syncthreads();
    int f64 = flags[1];
    int e0 = blk * EPB;
    for (int i = t; i < EPB; i += 256) {
        int e = e0 + i;
        if (e < NE) atomicAdd(&h[e_dst(ei, e, f64) >> 9], 1);
    }
    __syncthreads();
    for (int i = t; i < NB2; i += 256) ghist[blk * NB2 + i] = h[i];
}

// kB: bucket bases + per-(block,bucket) private offsets (single block)
__global__ __launch_bounds__(256) void k_off(const int* __restrict__ ghist,
                                             int* __restrict__ cbase,
                                             int* __restrict__ offm,
                                             int* __restrict__ rowptr) {
    __shared__ int tot[NB2];
    int t = threadIdx.x;
    if (t < NB2) {
        int s = 0;
        for (int blk = 0; blk < NBLK; blk++) s += ghist[blk * NB2 + t];
        tot[t] = s;
    }
    __syncthreads();
    if (t == 0) {
        int run = 0;
        for (int b = 0; b < NB2; b++) { cbase[b] = run; run += tot[b]; }
        cbase[NB2] = run;
        rowptr[NN] = run;   // == NE
    }
    __syncthreads();
    if (t < NB2) {
        int run = cbase[t];
        for (int blk = 0; blk < NBLK; blk++) {
            offm[blk * NB2 + t] = run;
            run += ghist[blk * NB2 + t];
        }
    }
}

// kC: scatter packed (src | dst_lo9<<17) into bucket-grouped scratch,
//     each block writing only its own private sub-ranges (LDS cursors).
__global__ __launch_bounds__(256) void k_scatter(const int* __restrict__ ei,
                                                 const int* __restrict__ offm,
                                                 int* __restrict__ scratch,
                                                 const int* __restrict__ flags) {
    __shared__ int cur[NB2];
    int blk = blockIdx.x, t = threadIdx.x;
    for (int i = t; i < NB2; i += 256) cur[i] = offm[blk * NB2 + i];
    __syncthreads();
    int f64 = flags[1];
    int e0 = blk * EPB;
    for (int i = t; i < EPB; i += 256) {
        int e = e0 + i;
        if (e < NE) {
            int d = e_dst(ei, e, f64);
            int s = e_src(ei, e, f64);
            int p = atomicAdd(&cur[d >> 9], 1);
            p = min(max(p, 0), NE - 1);
            scratch[p] = s | ((d & 511) << 17);
        }
    }
}

// kD: one block per bucket: local 512-hist + scan -> rowptr + dis + csr place.
__global__ __launch_bounds__(256) void k_build(const int* __restrict__ scratch,
                                               const int* __restrict__ cbase,
                                               int* __restrict__ rowptr,
                                               float* __restrict__ dis,
                                               int* __restrict__ csr) {
    __shared__ int hist[512];
    __shared__ int base[512];
    __shared__ int sd[256];
    int b = blockIdx.x, t = threadIdx.x;
    int n0 = b << 9;
    int s0 = cbase[b], s1 = cbase[b + 1];
    hist[t] = 0; hist[t + 256] = 0;
    __syncthreads();
    for (int i = s0 + t; i < s1; i += 256) {
        int dlo = (scratch[i] >> 17) & 511;
        atomicAdd(&hist[dlo], 1);
    }
    __syncthreads();
    int v0 = hist[2 * t], v1 = hist[2 * t + 1];
    int s = v0 + v1;
    sd[t] = s; __syncthreads();
    for (int o = 1; o < 256; o <<= 1) {
        int add = (t >= o) ? sd[t - o] : 0;
        __syncthreads();
        sd[t] += add;
        __syncthreads();
    }
    int run = s0 + sd[t] - s;     // exclusive prefix for local pair 2t
    base[2 * t] = run;
    base[2 * t + 1] = run + v0;
    // rowptr + dis for this bucket's nodes
    int n = n0 + 2 * t;
    if (n < NN) {
        rowptr[n] = run;
        dis[n] = rsqrtf((float)v0 + 1.0f);
    }
    if (n + 1 < NN) {
        rowptr[n + 1] = run + v0;
        dis[n + 1] = rsqrtf((float)v1 + 1.0f);
    }
    __syncthreads();
    for (int i = s0 + t; i < s1; i += 256) {
        int v = scratch[i];
        int dlo = (v >> 17) & 511;
        int p = atomicAdd(&base[dlo], 1);
        p = min(max(p, 0), NE - 1);
        csr[p] = v & 0x1FFFF;
    }
}

// ------------- MFMA GEMM: O[NNxCOLS] = A(fp8,128) @ W(bf16 frag-order) --------
template <int NCT>    // NCT = COLS/16 (8 or 4)
__global__ __launch_bounds__(256) void k_xf_mfma(const unsigned char* __restrict__ A,
                                                 const unsigned short* __restrict__ Wf,
                                                 unsigned char* __restrict__ O) {
    __shared__ unsigned short wl[NCT * 4 * 64 * 8];
    int t = threadIdx.x;
    int n0 = blockIdx.x * 64;
    {
        const uint4* wg = (const uint4*)Wf;
        uint4* wld = (uint4*)wl;
#pragma unroll
        for (int i = 0; i < NCT; i++) wld[i * 256 + t] = wg[i * 256 + t];
    }
    __syncthreads();
    int w = t >> 6, l = t & 63;
    int quad = l >> 4, m = l & 15;
    int arow = n0 + w * 16 + m;
    const unsigned char* ap = A + (size_t)arow * 128 + quad * 8;
    f32x4 acc[NCT];
#pragma unroll
    for (int c = 0; c < NCT; c++) acc[c] = (f32x4){0.0f, 0.0f, 0.0f, 0.0f};
#pragma unroll
    for (int kc = 0; kc < 4; kc++) {
        uint2 g = *(const uint2*)(ap + kc * 32);
        float o[8];
        f8d4(g.x, o); f8d4(g.y, o + 4);
        union { unsigned u[4]; bf16x8 v; } fr;
        fr.u[0] = bfpack(o[0], o[1]);
        fr.u[1] = bfpack(o[2], o[3]);
        fr.u[2] = bfpack(o[4], o[5]);
        fr.u[3] = bfpack(o[6], o[7]);
#pragma unroll
        for (int c = 0; c < NCT; c++) {
            bf16x8 bw = *(const bf16x8*)&wl[((kc * NCT + c) * 64 + l) * 8];
            acc[c] = __builtin_amdgcn_mfma_f32_16x16x32_bf16(fr.v, bw, acc[c], 0, 0, 0);
        }
    }
    int orow0 = n0 + w * 16 + quad * 4;
#pragma unroll
    for (int c = 0; c < NCT; c++) {
        int col = c * 16 + m;
#pragma unroll
        for (int r = 0; r < 4; r++) {
            int row = orow0 + r;
            if (row < NN) O[(size_t)row * (NCT * 16) + col] = f8e1(acc[c][r]);
        }
    }
}

// ---------------- agg, F=128: H = relu?(Anorm @ T + b), fp8 -> fp8 -----------
template <bool RELU>
__global__ __launch_bounds__(256) void k_agg128(const unsigned char* __restrict__ T,
                                                const int* __restrict__ rowptr,
                                                const int* __restrict__ csr,
                                                const float* __restrict__ dis,
                                                const float* __restrict__ bias,
                                                unsigned char* __restrict__ H) {
    int n = blockIdx.x * 4 + (threadIdx.x >> 6);
    int lane = threadIdx.x & 63;
    float dn = dis[n];
    int s0 = rowptr[n], s1 = rowptr[n + 1];
    s0 = min(max(s0, 0), NE); s1 = min(max(s1, s0), NE);
    unsigned short rself = *(const unsigned short*)(T + (size_t)n * 128 + lane * 2);
    float sx, sy; f8d2(rself, sx, sy);
    float dnn = dn * dn;
    float a0 = sx * dnn + bias[2 * lane];
    float a1 = sy * dnn + bias[2 * lane + 1];
    float b0 = 0, b1 = 0, c0 = 0, c1 = 0, d0 = 0, d1 = 0;
    for (int base = s0; base < s1; base += 64) {
        int m = min(64, s1 - base);
        int idx = 0; float wv = 0.0f;
        if (lane < m) {
            int ss = csr[base + lane];
            ss = min(max(ss, 0), NN - 1);
            idx = ss; wv = dis[ss] * dn;
        }
        unsigned wbits = __float_as_uint(wv);
        int j = 0;
        for (; j + 4 <= m; j += 4) {
            int sa = __builtin_amdgcn_readlane(idx, j);
            int sb = __builtin_amdgcn_readlane(idx, j + 1);
            int sc = __builtin_amdgcn_readlane(idx, j + 2);
            int sd = __builtin_amdgcn_readlane(idx, j + 3);
            float wa = __uint_as_float(__builtin_amdgcn_readlane(wbits, j));
            float wb = __uint_as_float(__builtin_amdgcn_readlane(wbits, j + 1));
            float wc = __uint_as_float(__builtin_amdgcn_readlane(wbits, j + 2));
            float wd = __uint_as_float(__builtin_amdgcn_readlane(wbits, j + 3));
            unsigned short ra = *(const unsigned short*)(T + (size_t)sa * 128 + lane * 2);
            unsigned short rb = *(const unsigned short*)(T + (size_t)sb * 128 + lane * 2);
            unsigned short rc = *(const unsigned short*)(T + (size_t)sc * 128 + lane * 2);
            unsigned short rd = *(const unsigned short*)(T + (size_t)sd * 128 + lane * 2);
            float x0, x1;
            f8d2(ra, x0, x1); a0 += x0 * wa; a1 += x1 * wa;
            f8d2(rb, x0, x1); b0 += x0 * wb; b1 += x1 * wb;
            f8d2(rc, x0, x1); c0 += x0 * wc; c1 += x1 * wc;
            f8d2(rd, x0, x1); d0 += x0 * wd; d1 += x1 * wd;
        }
        for (; j < m; j++) {
            int sa = __builtin_amdgcn_readlane(idx, j);
            float wa = __uint_as_float(__builtin_amdgcn_readlane(wbits, j));
            unsigned short ra = *(const unsigned short*)(T + (size_t)sa * 128 + lane * 2);
            float x0, x1; f8d2(ra, x0, x1);
            a0 += x0 * wa; a1 += x1 * wa;
        }
    }
    a0 += b0 + c0 + d0; a1 += b1 + c1 + d1;
    if (RELU) { a0 = fmaxf(a0, 0.0f); a1 = fmaxf(a1, 0.0f); }
    *(unsigned short*)(H + (size_t)n * 128 + lane * 2) = f8e2(a0, a1);
}

// ---------------- agg, F=64 final: h3 = Anorm @ T3 + b3 -> bf16 --------------
__global__ __launch_bounds__(256) void k_agg64(const unsigned char* __restrict__ T,
                                               const int* __restrict__ rowptr,
                                               const int* __restrict__ csr,
                                               const float* __restrict__ dis,
                                               const float* __restrict__ bias,
                                               unsigned short* __restrict__ Hb) {
    int n = blockIdx.x * 4 + (threadIdx.x >> 6);
    int lane = threadIdx.x & 63;
    float dn = dis[n];
    int s0 = rowptr[n], s1 = rowptr[n + 1];
    s0 = min(max(s0, 0), NE); s1 = min(max(s1, s0), NE);
    float a0 = f8d1(T[(size_t)n * 64 + lane]) * (dn * dn) + bias[lane];
    float b0 = 0, c0 = 0, d0 = 0;
    for (int base = s0; base < s1; base += 64) {
        int m = min(64, s1 - base);
        int idx = 0; float wv = 0.0f;
        if (lane < m) {
            int ss = csr[base + lane];
            ss = min(max(ss, 0), NN - 1);
            idx = ss; wv = dis[ss] * dn;
        }
        unsigned wbits = __float_as_uint(wv);
        int j = 0;
        for (; j + 4 <= m; j += 4) {
            int sa = __builtin_amdgcn_readlane(idx, j);
            int sb = __builtin_amdgcn_readlane(idx, j + 1);
            int sc = __builtin_amdgcn_readlane(idx, j + 2);
            int sd = __builtin_amdgcn_readlane(idx, j + 3);
            float wa = __uint_as_float(__builtin_amdgcn_readlane(wbits, j));
            float wb = __uint_as_float(__builtin_amdgcn_readlane(wbits, j + 1));
            float wc = __uint_as_float(__builtin_amdgcn_readlane(wbits, j + 2));
            float wd = __uint_as_float(__builtin_amdgcn_readlane(wbits, j + 3));
            unsigned ra = T[(size_t)sa * 64 + lane];
            unsigned rb = T[(size_t)sb * 64 + lane];
            unsigned rc = T[(size_t)sc * 64 + lane];
            unsigned rd = T[(size_t)sd * 64 + lane];
            a0 += f8d1(ra) * wa;
            b0 += f8d1(rb) * wb;
            c0 += f8d1(rc) * wc;
            d0 += f8d1(rd) * wd;
        }
        for (; j < m; j++) {
            int sa = __builtin_amdgcn_readlane(idx, j);
            float wa = __uint_as_float(__builtin_amdgcn_readlane(wbits, j));
            a0 += f8d1(T[(size_t)sa * 64 + lane]) * wa;
        }
    }
    a0 += b0 + c0 + d0;
    Hb[(size_t)n * 64 + lane] = __bfloat16_as_ushort(__float2bfloat16(a0));
}

// ---------------- attention pooling on Hb (bf16-as-ushort) ----------------
__global__ void k_colsum(const unsigned short* __restrict__ h3, float* __restrict__ colsum) {
    int lane = threadIdx.x & 63;
    int wave = (blockIdx.x * blockDim.x + threadIdx.x) >> 6;
    int nw = (gridDim.x * blockDim.x) >> 6;
    float acc = 0.0f;
    for (int n = wave; n < NN; n += nw) acc += bfu(h3[(size_t)n * 64 + lane]);
    __shared__ float sd[256];
    sd[threadIdx.x] = acc; __syncthreads();
    if (threadIdx.x < 64)
        atomicAdd(&colsum[threadIdx.x],
                  sd[threadIdx.x] + sd[threadIdx.x + 64] + sd[threadIdx.x + 128] + sd[threadIdx.x + 192]);
}

__global__ void k_ctx(const float* __restrict__ colsum, const float* __restrict__ Wa,
                      float* __restrict__ ctx) {
    __shared__ float ms[64];
    int j = threadIdx.x;
    ms[j] = colsum[j] * (1.0f / NN);
    __syncthreads();
    float s = 0.0f;
#pragma unroll
    for (int k = 0; k < 64; k++) s += ms[k] * Wa[k * 64 + j];
    ctx[j] = tanhf(s);
}

__global__ void k_pool(const unsigned short* __restrict__ h3, const float* __restrict__ ctx,
                       float* __restrict__ pooled) {
    int lane = threadIdx.x & 63;
    int wave = (blockIdx.x * blockDim.x + threadIdx.x) >> 6;
    int nw = (gridDim.x * blockDim.x) >> 6;
    float c = ctx[lane];
    float acc = 0.0f;
    for (int n = wave; n < NN; n += nw) {
        float v = bfu(h3[(size_t)n * 64 + lane]);
        float p = v * c;
#pragma unroll
        for (int m = 32; m > 0; m >>= 1) p += __shfl_xor(p, m, 64);
        float score = 1.0f / (1.0f + expf(-p));
        acc += score * v;
    }
    __shared__ float sd[256];
    sd[threadIdx.x] = acc; __syncthreads();
    if (threadIdx.x < 64)
        atomicAdd(&pooled[threadIdx.x],
                  sd[threadIdx.x] + sd[threadIdx.x + 64] + sd[threadIdx.x + 128] + sd[threadIdx.x + 192]);
}

// ---------------- final output write ----------------
__global__ void k_out(const unsigned short* __restrict__ h3, const float* __restrict__ pooled,
                      void* __restrict__ out, const int* __restrict__ flags) {
    long long i = (long long)blockIdx.x * blockDim.x + threadIdx.x;
    if (i >= 6400064LL) return;
    float v = (i < 6400000LL) ? bfu(h3[i]) : pooled[i - 6400000LL];
    if (flags[0]) ((float*)out)[i] = v;
    else          ((unsigned short*)out)[i] = __bfloat16_as_ushort(__float2bfloat16(v));
}

// ---------------- workspace layout (~21.5 MB) ----------------
static constexpr size_t AL(size_t x) { return (x + 255) & ~size_t(255); }
static constexpr size_t OFF_FLAGS  = 0;
static constexpr size_t OFF_RAW    = OFF_FLAGS + 256;
static constexpr size_t OFF_GHIST  = OFF_RAW + 256;
static constexpr size_t OFF_OFFM   = OFF_GHIST + AL((size_t)NBLK * NB2 * 4);
static constexpr size_t OFF_CBASE  = OFF_OFFM + AL((size_t)NBLK * NB2 * 4);
static constexpr size_t OFF_ROWPTR = OFF_CBASE + AL((NB2 + 1) * 4);
static constexpr size_t OFF_CSR    = OFF_ROWPTR + AL((NN + 1) * 4);
static constexpr size_t OFF_DIS    = OFF_CSR + AL((size_t)NE * 4);
static constexpr size_t OFF_P      = OFF_DIS + AL(NN * 4);     // NR*128 fp8; also scatter scratch; also bf16 h3
static constexpr size_t OFF_W1B    = OFF_P + AL((size_t)NR * 128);
static constexpr size_t OFF_W2B    = OFF_W1B + AL(16384 * 2);
static constexpr size_t OFF_W3B    = OFF_W2B + AL(16384 * 2);
static constexpr size_t OFF_B1F    = OFF_W3B + AL(8192 * 2);
static constexpr size_t OFF_B2F    = OFF_B1F + AL(128 * 4);
static constexpr size_t OFF_B3F    = OFF_B2F + AL(128 * 4);
static constexpr size_t OFF_WAF    = OFF_B3F + AL(64 * 4);
static constexpr size_t OFF_COLSUM = OFF_WAF + AL(4096 * 4);
static constexpr size_t OFF_POOLED = OFF_COLSUM + AL(64 * 4);
static constexpr size_t OFF_CTX    = OFF_POOLED + AL(64 * 4);

extern "C" void kernel_launch(void* const* d_in, const int* in_sizes, int n_in,
                              void* d_out, int out_size, void* d_ws, size_t ws_size,
                              hipStream_t stream) {
    const int* ei = (const int*)d_in[0];
    const void* x  = d_in[1];
    const void* W1 = d_in[2];
    const void* b1 = d_in[3];
    const void* W2 = d_in[4];
    const void* b2 = d_in[5];
    const void* W3 = d_in[6];
    const void* b3 = d_in[7];
    const void* Wa = d_in[8];

    char* ws = (char*)d_ws;
    int*   flags  = (int*)(ws + OFF_FLAGS);
    int*   raw    = (int*)(ws + OFF_RAW);
    int*   ghist  = (int*)(ws + OFF_GHIST);
    int*   offm   = (int*)(ws + OFF_OFFM);
    int*   cbase  = (int*)(ws + OFF_CBASE);
    int*   rowptr = (int*)(ws + OFF_ROWPTR);
    int*   csr    = (int*)(ws + OFF_CSR);
    float* dis    = (float*)(ws + OFF_DIS);
    unsigned char*  P    = (unsigned char*)(ws + OFF_P);
    int*            scrA = (int*)(ws + OFF_P);             // scatter scratch (6.4 MB < 12.8)
    unsigned short* Hb   = (unsigned short*)(ws + OFF_P);  // bf16 h3 after L3
    unsigned short* W1b = (unsigned short*)(ws + OFF_W1B);
    unsigned short* W2b = (unsigned short*)(ws + OFF_W2B);
    unsigned short* W3b = (unsigned short*)(ws + OFF_W3B);
    float* b1f    = (float*)(ws + OFF_B1F);
    float* b2f    = (float*)(ws + OFF_B2F);
    float* b3f    = (float*)(ws + OFF_B3F);
    float* Waf    = (float*)(ws + OFF_WAF);
    float* colsum = (float*)(ws + OFF_COLSUM);
    float* pooled = (float*)(ws + OFF_POOLED);
    float* ctx    = (float*)(ws + OFF_CTX);

    unsigned char* Q = (unsigned char*)d_out;   // d_out doubles as T-scratch (12.8 MB)

    hipMemsetAsync(raw, 0, 256, stream);
    hipMemsetAsync(colsum, 0, 64 * 4, stream);
    hipMemsetAsync(pooled, 0, 64 * 4, stream);

    k_probe1<<<256, 256, 0, stream>>>((const unsigned short*)x, ei, raw);
    k_probe2<<<1, 64, 0, stream>>>(raw, flags);
    cvt_params<<<64, 256, 0, stream>>>(W1, b1, W2, b2, W3, b3, Wa,
                                       W1b, W2b, W3b, b1f, b2f, b3f, Waf, flags);

    // atomic-free CSR build
    k_hist<<<NBLK, 256, 0, stream>>>(ei, ghist, flags);
    k_off<<<1, 256, 0, stream>>>(ghist, cbase, offm, rowptr);
    k_scatter<<<NBLK, 256, 0, stream>>>(ei, offm, scrA, flags);
    k_build<<<NB2, 256, 0, stream>>>(scrA, cbase, rowptr, dis, csr);

    // x -> fp8 P (overwrites scatter scratch)
    k_cvtx<<<(NN * 128 / 4 + 255) / 256, 256, 0, stream>>>(x, P, flags);

    // L1: T = P@W1 (Q, MFMA) ; P = relu(Anorm@T + b1)
    k_xf_mfma<8><<<NR / 64, 256, 0, stream>>>(P, W1b, Q);
    k_agg128<true><<<NN / 4, 256, 0, stream>>>(Q, rowptr, csr, dis, b1f, P);
    // L2
    k_xf_mfma<8><<<NR / 64, 256, 0, stream>>>(P, W2b, Q);
    k_agg128<true><<<NN / 4, 256, 0, stream>>>(Q, rowptr, csr, dis, b2f, P);
    // L3: T3 = P@W3 (Q, 64 cols) ; Hb = Anorm@T3 + b3 (bf16, overwrites P)
    k_xf_mfma<4><<<NR / 64, 256, 0, stream>>>(P, W3b, Q);
    k_agg64<<<NN / 4, 256, 0, stream>>>(Q, rowptr, csr, dis, b3f, Hb);

    // attention pooling
    k_colsum<<<256, 256, 0, stream>>>(Hb, colsum);
    k_ctx<<<1, 64, 0, stream>>>(colsum, Waf, ctx);
    k_pool<<<256, 256, 0, stream>>>(Hb, ctx, pooled);

    // final output
    k_out<<<(6400064 + 255) / 256, 256, 0, stream>>>(Hb, pooled, d_out, flags);
}

// Round 8
// 449.759 us; speedup vs baseline: 3.5020x; 1.0940x over previous
//
#include <hip/hip_runtime.h>
#include <hip/hip_bf16.h>

#define NN 100000
#define NE 1600000
#define NR 100032            // NN rounded to 64-row blocks (table alloc rows)
#define NB2 196              // coarse buckets = ceil(NN/512)
#define NBLK 391             // hist/scatter blocks = ceil(NE/4096)
#define EPB 4096             // edges per hist/scatter block

#if defined(__has_builtin)
#  if __has_builtin(__builtin_amdgcn_cvt_pk_f32_fp8) && \
      __has_builtin(__builtin_amdgcn_cvt_pk_fp8_f32) && \
      __has_builtin(__builtin_amdgcn_cvt_f32_fp8)
#    define HWF8 1
#  endif
#endif

typedef float f32x2 __attribute__((ext_vector_type(2)));
typedef float f32x4 __attribute__((ext_vector_type(4)));
typedef short bf16x8 __attribute__((ext_vector_type(8)));

static __device__ __forceinline__ float bf2f(__hip_bfloat16 v) { return __bfloat162float(v); }
static __device__ __forceinline__ float bfu(unsigned short w) {
    return __uint_as_float((unsigned)w << 16);
}

// ---------------- fp8 e4m3 software codec (fallback, validated r3/r4) ---------
static __device__ __forceinline__ float f8d_sw(unsigned b) {
    unsigned e = (b >> 3) & 15u, m = b & 7u;
    float mag;
    if (e == 0) mag = (float)m * 0.001953125f;
    else        mag = __uint_as_float(((e + 120u) << 23) | (m << 20));
    return (b & 0x80u) ? -mag : mag;
}
static __device__ __forceinline__ unsigned char f8e_sw(float x) {
    unsigned u = __float_as_uint(x);
    unsigned s = (u >> 31) << 7;
    unsigned au = u & 0x7fffffffu;
    if (au >= 0x43E00000u) return (unsigned char)(s | 0x7Eu);
    if (au <  0x3A800000u) return (unsigned char)s;
    if (au <  0x3C800000u) {
        float a = __uint_as_float(au);
        int m = (int)rintf(a * 512.0f);
        if (m >= 8) return (unsigned char)(s | 0x08u);
        return (unsigned char)(s | (unsigned)m);
    }
    au += 0x80000u;
    if (au >= 0x43E00000u) return (unsigned char)(s | 0x7Eu);
    unsigned e = (au >> 23) - 120u;
    unsigned m = (au >> 20) & 7u;
    return (unsigned char)(s | (e << 3) | m);
}

// ---------------- fp8 helpers (HW if available) ----------------
static __device__ __forceinline__ float f8d1(unsigned b) {
#ifdef HWF8
    return __builtin_amdgcn_cvt_f32_fp8((int)b, 0);
#else
    return f8d_sw(b);
#endif
}
static __device__ __forceinline__ void f8d2(unsigned short v, float& x0, float& x1) {
#ifdef HWF8
    f32x2 r = __builtin_amdgcn_cvt_pk_f32_fp8((int)(unsigned)v, false);
    x0 = r.x; x1 = r.y;
#else
    x0 = f8d_sw(v & 255u); x1 = f8d_sw(v >> 8);
#endif
}
static __device__ __forceinline__ void f8d4(unsigned u, float* o) {
#ifdef HWF8
    f32x2 lo = __builtin_amdgcn_cvt_pk_f32_fp8((int)u, false);
    f32x2 hi = __builtin_amdgcn_cvt_pk_f32_fp8((int)u, true);
    o[0] = lo.x; o[1] = lo.y; o[2] = hi.x; o[3] = hi.y;
#else
    o[0] = f8d_sw(u & 255u); o[1] = f8d_sw((u >> 8) & 255u);
    o[2] = f8d_sw((u >> 16) & 255u); o[3] = f8d_sw(u >> 24);
#endif
}
static __device__ __forceinline__ unsigned short f8e2(float a, float b) {
#ifdef HWF8
    float ca = fminf(fmaxf(a, -448.0f), 448.0f);
    float cb = fminf(fmaxf(b, -448.0f), 448.0f);
    int p = __builtin_amdgcn_cvt_pk_fp8_f32(ca, cb, 0, false);
    return (unsigned short)(p & 0xFFFF);
#else
    return (unsigned short)f8e_sw(a) | ((unsigned short)f8e_sw(b) << 8);
#endif
}
static __device__ __forceinline__ unsigned char f8e1(float a) {
    return (unsigned char)(f8e2(a, 0.0f) & 0xFF);
}
// f32 -> bf16 bits by truncation (EXACT for values that came from fp8 e4m3)
static __device__ __forceinline__ unsigned bfpack(float lo, float hi) {
    return (__float_as_uint(lo) >> 16) | (__float_as_uint(hi) & 0xFFFF0000u);
}

// ---------------- dtype probes (parallel) ----------------
__global__ void k_probe1(const unsigned short* __restrict__ xw,
                         const int* __restrict__ ei, int* __restrict__ raw) {
    int i = blockIdx.x * 256 + threadIdx.x;    // 65536 probes
    int nan = ((xw[i] & 0x7F80u) == 0x7F80u) ? 1 : 0;
    int odd = (ei[2 * i + 1] != 0) ? 1 : 0;
    unsigned long long bn = __ballot(nan);
    unsigned long long bo = __ballot(odd);
    if ((threadIdx.x & 63) == 0) {
        if (bn) atomicAdd(&raw[0], __popcll(bn));
        if (bo) atomicAdd(&raw[1], __popcll(bo));
    }
}
__global__ void k_probe2(const int* __restrict__ raw, int* __restrict__ flags) {
    if (threadIdx.x == 0) {
        flags[0] = (raw[0] > 0) ? 1 : 0;   // x/weights are f32
        flags[1] = (raw[1] == 0) ? 1 : 0;  // edge_index is int64
    }
}

static __device__ __forceinline__ int e_src(const int* ei, int e, int f64) {
    int v = f64 ? ei[2 * e] : ei[e];
    return min(max(v, 0), NN - 1);
}
static __device__ __forceinline__ int e_dst(const int* ei, int e, int f64) {
    int v = f64 ? ei[2 * (NE + e)] : ei[NE + e];
    return min(max(v, 0), NN - 1);
}
static __device__ __forceinline__ float ldx(const void* p, long long i, int f32) {
    return f32 ? ((const float*)p)[i] : bf2f(((const __hip_bfloat16*)p)[i]);
}

// ------------- parameter conversion: W -> bf16 in MFMA-frag order -------------
__global__ void cvt_params(const void* W1, const void* b1, const void* W2, const void* b2,
                           const void* W3, const void* b3, const void* Wa,
                           unsigned short* W1b, unsigned short* W2b, unsigned short* W3b,
                           float* b1f, float* b2f, float* b3f, float* Waf,
                           const int* flags) {
    int i = blockIdx.x * blockDim.x + threadIdx.x;
    int f = flags[0];
    if (i < 16384) {
        int j = i & 7, l = (i >> 3) & 63, c = (i >> 9) & 7, kc = i >> 12;
        int k = kc * 32 + ((l >> 4)) * 8 + j;
        int col = c * 16 + (l & 15);
        W1b[i] = __bfloat16_as_ushort(__float2bfloat16(ldx(W1, k * 128 + col, f)));
        W2b[i] = __bfloat16_as_ushort(__float2bfloat16(ldx(W2, k * 128 + col, f)));
    }
    if (i < 8192) {
        int j = i & 7, l = (i >> 3) & 63, c = (i >> 9) & 3, kc = i >> 11;
        int k = kc * 32 + ((l >> 4)) * 8 + j;
        int col = c * 16 + (l & 15);
        W3b[i] = __bfloat16_as_ushort(__float2bfloat16(ldx(W3, k * 64 + col, f)));
    }
    if (i < 4096)  Waf[i] = ldx(Wa, i, f);
    if (i < 128)   { b1f[i] = ldx(b1, i, f); b2f[i] = ldx(b2, i, f); }
    if (i < 64)    b3f[i] = ldx(b3, i, f);
}

// ---------------- x -> fp8 table P ----------------
__global__ void k_cvtx(const void* __restrict__ x, unsigned char* __restrict__ P,
                       const int* __restrict__ flags) {
    int i = blockIdx.x * blockDim.x + threadIdx.x;
    if (i >= (NN * 128) / 4) return;
    unsigned pk;
    if (flags[0]) {
        float4 v = ((const float4*)x)[i];
        pk = (unsigned)f8e2(v.x, v.y) | ((unsigned)f8e2(v.z, v.w) << 16);
    } else {
        ushort4 v = ((const ushort4*)x)[i];
        pk = (unsigned)f8e2(bfu(v.x), bfu(v.y)) | ((unsigned)f8e2(bfu(v.z), bfu(v.w)) << 16);
    }
    ((unsigned*)P)[i] = pk;
}

// ======== CSR build: atomic-free multisplit (validated r7) ========
__global__ __launch_bounds__(256) void k_hist(const int* __restrict__ ei,
                                              int* __restrict__ ghist,
                                              const int* __restrict__ flags) {
    __shared__ int h[NB2];
    int blk = blockIdx.x, t = threadIdx.x;
    for (int i = t; i < NB2; i += 256) h[i] = 0;
    __syncthreads();
    int f64 = flags[1];
    int e0 = blk * EPB;
    for (int i = t; i < EPB; i += 256) {
        int e = e0 + i;
        if (e < NE) atomicAdd(&h[e_dst(ei, e, f64) >> 9], 1);
    }
    __syncthreads();
    for (int i = t; i < NB2; i += 256) ghist[blk * NB2 + i] = h[i];
}

__global__ __launch_bounds__(256) void k_off(const int* __restrict__ ghist,
                                             int* __restrict__ cbase,
                                             int* __restrict__ offm,
                                             int* __restrict__ rowptr) {
    __shared__ int tot[NB2];
    int t = threadIdx.x;
    if (t < NB2) {
        int s = 0;
        for (int blk = 0; blk < NBLK; blk++) s += ghist[blk * NB2 + t];
        tot[t] = s;
    }
    __syncthreads();
    if (t == 0) {
        int run = 0;
        for (int b = 0; b < NB2; b++) { cbase[b] = run; run += tot[b]; }
        cbase[NB2] = run;
        rowptr[NN] = run;   // == NE
    }
    __syncthreads();
    if (t < NB2) {
        int run = cbase[t];
        for (int blk = 0; blk < NBLK; blk++) {
            offm[blk * NB2 + t] = run;
            run += ghist[blk * NB2 + t];
        }
    }
}

__global__ __launch_bounds__(256) void k_scatter(const int* __restrict__ ei,
                                                 const int* __restrict__ offm,
                                                 int* __restrict__ scratch,
                                                 const int* __restrict__ flags) {
    __shared__ int cur[NB2];
    int blk = blockIdx.x, t = threadIdx.x;
    for (int i = t; i < NB2; i += 256) cur[i] = offm[blk * NB2 + i];
    __syncthreads();
    int f64 = flags[1];
    int e0 = blk * EPB;
    for (int i = t; i < EPB; i += 256) {
        int e = e0 + i;
        if (e < NE) {
            int d = e_dst(ei, e, f64);
            int s = e_src(ei, e, f64);
            int p = atomicAdd(&cur[d >> 9], 1);
            p = min(max(p, 0), NE - 1);
            scratch[p] = s | ((d & 511) << 17);
        }
    }
}

__global__ __launch_bounds__(256) void k_build(const int* __restrict__ scratch,
                                               const int* __restrict__ cbase,
                                               int* __restrict__ rowptr,
                                               float* __restrict__ dis,
                                               int* __restrict__ csr) {
    __shared__ int hist[512];
    __shared__ int base[512];
    __shared__ int sd[256];
    int b = blockIdx.x, t = threadIdx.x;
    int n0 = b << 9;
    int s0 = cbase[b], s1 = cbase[b + 1];
    hist[t] = 0; hist[t + 256] = 0;
    __syncthreads();
    for (int i = s0 + t; i < s1; i += 256) {
        int dlo = (scratch[i] >> 17) & 511;
        atomicAdd(&hist[dlo], 1);
    }
    __syncthreads();
    int v0 = hist[2 * t], v1 = hist[2 * t + 1];
    int s = v0 + v1;
    sd[t] = s; __syncthreads();
    for (int o = 1; o < 256; o <<= 1) {
        int add = (t >= o) ? sd[t - o] : 0;
        __syncthreads();
        sd[t] += add;
        __syncthreads();
    }
    int run = s0 + sd[t] - s;
    base[2 * t] = run;
    base[2 * t + 1] = run + v0;
    int n = n0 + 2 * t;
    if (n < NN) {
        rowptr[n] = run;
        dis[n] = rsqrtf((float)v0 + 1.0f);
    }
    if (n + 1 < NN) {
        rowptr[n + 1] = run + v0;
        dis[n + 1] = rsqrtf((float)v1 + 1.0f);
    }
    __syncthreads();
    for (int i = s0 + t; i < s1; i += 256) {
        int v = scratch[i];
        int dlo = (v >> 17) & 511;
        int p = atomicAdd(&base[dlo], 1);
        p = min(max(p, 0), NE - 1);
        csr[p] = v & 0x1FFFF;
    }
}

// ------------- MFMA GEMM: O[NNxCOLS] = A(fp8,128) @ W(bf16 frag-order) --------
template <int NCT>    // NCT = COLS/16 (8 or 4)
__global__ __launch_bounds__(256) void k_xf_mfma(const unsigned char* __restrict__ A,
                                                 const unsigned short* __restrict__ Wf,
                                                 unsigned char* __restrict__ O) {
    __shared__ unsigned short wl[NCT * 4 * 64 * 8];
    int t = threadIdx.x;
    int n0 = blockIdx.x * 64;
    {
        const uint4* wg = (const uint4*)Wf;
        uint4* wld = (uint4*)wl;
#pragma unroll
        for (int i = 0; i < NCT; i++) wld[i * 256 + t] = wg[i * 256 + t];
    }
    __syncthreads();
    int w = t >> 6, l = t & 63;
    int quad = l >> 4, m = l & 15;
    int arow = n0 + w * 16 + m;
    const unsigned char* ap = A + (size_t)arow * 128 + quad * 8;
    f32x4 acc[NCT];
#pragma unroll
    for (int c = 0; c < NCT; c++) acc[c] = (f32x4){0.0f, 0.0f, 0.0f, 0.0f};
#pragma unroll
    for (int kc = 0; kc < 4; kc++) {
        uint2 g = *(const uint2*)(ap + kc * 32);
        float o[8];
        f8d4(g.x, o); f8d4(g.y, o + 4);
        union { unsigned u[4]; bf16x8 v; } fr;
        fr.u[0] = bfpack(o[0], o[1]);
        fr.u[1] = bfpack(o[2], o[3]);
        fr.u[2] = bfpack(o[4], o[5]);
        fr.u[3] = bfpack(o[6], o[7]);
#pragma unroll
        for (int c = 0; c < NCT; c++) {
            bf16x8 bw = *(const bf16x8*)&wl[((kc * NCT + c) * 64 + l) * 8];
            acc[c] = __builtin_amdgcn_mfma_f32_16x16x32_bf16(fr.v, bw, acc[c], 0, 0, 0);
        }
    }
    int orow0 = n0 + w * 16 + quad * 4;
#pragma unroll
    for (int c = 0; c < NCT; c++) {
        int col = c * 16 + m;
#pragma unroll
        for (int r = 0; r < 4; r++) {
            int row = orow0 + r;
            if (row < NN) O[(size_t)row * (NCT * 16) + col] = f8e1(acc[c][r]);
        }
    }
}

// ---- agg, F=128: H = relu?((Anorm@T) + b), fp8->fp8; unroll 8, 32-bit addr ---
template <bool RELU>
__global__ __launch_bounds__(256) void k_agg128(const unsigned char* __restrict__ Tb,
                                                const int* __restrict__ rowptr,
                                                const int* __restrict__ csr,
                                                const float* __restrict__ dis,
                                                const float* __restrict__ bias,
                                                unsigned char* __restrict__ H) {
    const unsigned short* T16 = (const unsigned short*)Tb;
    int n = blockIdx.x * 4 + (threadIdx.x >> 6);
    int lane = threadIdx.x & 63;
    float dn = dis[n];
    int s0 = rowptr[n], s1 = rowptr[n + 1];
    s0 = min(max(s0, 0), NE); s1 = min(max(s1, s0), NE);
    unsigned short rself = T16[((unsigned)n << 6) + lane];
    float sx, sy; f8d2(rself, sx, sy);
    float a0 = 0, a1 = 0, b0 = 0, b1 = 0, c0 = 0, c1 = 0, d0 = 0, d1 = 0;
    for (int base = s0; base < s1; base += 64) {
        int m = min(64, s1 - base);
        int idx = 0; float wv = 0.0f;
        if (lane < m) {
            int ss = csr[base + lane];
            ss = min(max(ss, 0), NN - 1);
            idx = ss; wv = dis[ss];            // dn folded out of the loop
        }
        unsigned wbits = __float_as_uint(wv);
        int j = 0;
        for (; j + 8 <= m; j += 8) {
            int i0 = __builtin_amdgcn_readlane(idx, j);
            int i1 = __builtin_amdgcn_readlane(idx, j + 1);
            int i2 = __builtin_amdgcn_readlane(idx, j + 2);
            int i3 = __builtin_amdgcn_readlane(idx, j + 3);
            int i4 = __builtin_amdgcn_readlane(idx, j + 4);
            int i5 = __builtin_amdgcn_readlane(idx, j + 5);
            int i6 = __builtin_amdgcn_readlane(idx, j + 6);
            int i7 = __builtin_amdgcn_readlane(idx, j + 7);
            float w0 = __uint_as_float(__builtin_amdgcn_readlane(wbits, j));
            float w1 = __uint_as_float(__builtin_amdgcn_readlane(wbits, j + 1));
            float w2 = __uint_as_float(__builtin_amdgcn_readlane(wbits, j + 2));
            float w3 = __uint_as_float(__builtin_amdgcn_readlane(wbits, j + 3));
            float w4 = __uint_as_float(__builtin_amdgcn_readlane(wbits, j + 4));
            float w5 = __uint_as_float(__builtin_amdgcn_readlane(wbits, j + 5));
            float w6 = __uint_as_float(__builtin_amdgcn_readlane(wbits, j + 6));
            float w7 = __uint_as_float(__builtin_amdgcn_readlane(wbits, j + 7));
            unsigned short r0 = T16[((unsigned)i0 << 6) + lane];
            unsigned short r1 = T16[((unsigned)i1 << 6) + lane];
            unsigned short r2 = T16[((unsigned)i2 << 6) + lane];
            unsigned short r3 = T16[((unsigned)i3 << 6) + lane];
            unsigned short r4 = T16[((unsigned)i4 << 6) + lane];
            unsigned short r5 = T16[((unsigned)i5 << 6) + lane];
            unsigned short r6 = T16[((unsigned)i6 << 6) + lane];
            unsigned short r7 = T16[((unsigned)i7 << 6) + lane];
            float x0, x1;
            f8d2(r0, x0, x1); a0 += x0 * w0; a1 += x1 * w0;
            f8d2(r1, x0, x1); b0 += x0 * w1; b1 += x1 * w1;
            f8d2(r2, x0, x1); c0 += x0 * w2; c1 += x1 * w2;
            f8d2(r3, x0, x1); d0 += x0 * w3; d1 += x1 * w3;
            f8d2(r4, x0, x1); a0 += x0 * w4; a1 += x1 * w4;
            f8d2(r5, x0, x1); b0 += x0 * w5; b1 += x1 * w5;
            f8d2(r6, x0, x1); c0 += x0 * w6; c1 += x1 * w6;
            f8d2(r7, x0, x1); d0 += x0 * w7; d1 += x1 * w7;
        }
        for (; j < m; j++) {
            int sa = __builtin_amdgcn_readlane(idx, j);
            float wa = __uint_as_float(__builtin_amdgcn_readlane(wbits, j));
            unsigned short ra = T16[((unsigned)sa << 6) + lane];
            float x0, x1; f8d2(ra, x0, x1);
            a0 += x0 * wa; a1 += x1 * wa;
        }
    }
    float dnn = dn * dn;
    float t0 = (a0 + b0 + c0 + d0) * dn + sx * dnn + bias[2 * lane];
    float t1 = (a1 + b1 + c1 + d1) * dn + sy * dnn + bias[2 * lane + 1];
    if (RELU) { t0 = fmaxf(t0, 0.0f); t1 = fmaxf(t1, 0.0f); }
    *(unsigned short*)(H + ((size_t)n << 7) + lane * 2) = f8e2(t0, t1);
}

// ---- agg, F=64 final: h3 = (Anorm@T3) + b3 -> bf16; unroll 8 -----------------
__global__ __launch_bounds__(256) void k_agg64(const unsigned char* __restrict__ T,
                                               const int* __restrict__ rowptr,
                                               const int* __restrict__ csr,
                                               const float* __restrict__ dis,
                                               const float* __restrict__ bias,
                                               unsigned short* __restrict__ Hb) {
    int n = blockIdx.x * 4 + (threadIdx.x >> 6);
    int lane = threadIdx.x & 63;
    float dn = dis[n];
    int s0 = rowptr[n], s1 = rowptr[n + 1];
    s0 = min(max(s0, 0), NE); s1 = min(max(s1, s0), NE);
    float self = f8d1(T[((unsigned)n << 6) + lane]);
    float a0 = 0, b0 = 0, c0 = 0, d0 = 0;
    for (int base = s0; base < s1; base += 64) {
        int m = min(64, s1 - base);
        int idx = 0; float wv = 0.0f;
        if (lane < m) {
            int ss = csr[base + lane];
            ss = min(max(ss, 0), NN - 1);
            idx = ss; wv = dis[ss];
        }
        unsigned wbits = __float_as_uint(wv);
        int j = 0;
        for (; j + 8 <= m; j += 8) {
            int i0 = __builtin_amdgcn_readlane(idx, j);
            int i1 = __builtin_amdgcn_readlane(idx, j + 1);
            int i2 = __builtin_amdgcn_readlane(idx, j + 2);
            int i3 = __builtin_amdgcn_readlane(idx, j + 3);
            int i4 = __builtin_amdgcn_readlane(idx, j + 4);
            int i5 = __builtin_amdgcn_readlane(idx, j + 5);
            int i6 = __builtin_amdgcn_readlane(idx, j + 6);
            int i7 = __builtin_amdgcn_readlane(idx, j + 7);
            float w0 = __uint_as_float(__builtin_amdgcn_readlane(wbits, j));
            float w1 = __uint_as_float(__builtin_amdgcn_readlane(wbits, j + 1));
            float w2 = __uint_as_float(__builtin_amdgcn_readlane(wbits, j + 2));
            float w3 = __uint_as_float(__builtin_amdgcn_readlane(wbits, j + 3));
            float w4 = __uint_as_float(__builtin_amdgcn_readlane(wbits, j + 4));
            float w5 = __uint_as_float(__builtin_amdgcn_readlane(wbits, j + 5));
            float w6 = __uint_as_float(__builtin_amdgcn_readlane(wbits, j + 6));
            float w7 = __uint_as_float(__builtin_amdgcn_readlane(wbits, j + 7));
            unsigned r0 = T[((unsigned)i0 << 6) + lane];
            unsigned r1 = T[((unsigned)i1 << 6) + lane];
            unsigned r2 = T[((unsigned)i2 << 6) + lane];
            unsigned r3 = T[((unsigned)i3 << 6) + lane];
            unsigned r4 = T[((unsigned)i4 << 6) + lane];
            unsigned r5 = T[((unsigned)i5 << 6) + lane];
            unsigned r6 = T[((unsigned)i6 << 6) + lane];
            unsigned r7 = T[((unsigned)i7 << 6) + lane];
            a0 += f8d1(r0) * w0;
            b0 += f8d1(r1) * w1;
            c0 += f8d1(r2) * w2;
            d0 += f8d1(r3) * w3;
            a0 += f8d1(r4) * w4;
            b0 += f8d1(r5) * w5;
            c0 += f8d1(r6) * w6;
            d0 += f8d1(r7) * w7;
        }
        for (; j < m; j++) {
            int sa = __builtin_amdgcn_readlane(idx, j);
            float wa = __uint_as_float(__builtin_amdgcn_readlane(wbits, j));
            a0 += f8d1(T[((unsigned)sa << 6) + lane]) * wa;
        }
    }
    float t0 = (a0 + b0 + c0 + d0) * dn + self * (dn * dn) + bias[lane];
    Hb[((size_t)n << 6) + lane] = __bfloat16_as_ushort(__float2bfloat16(t0));
}

// ---------------- pooling v2: uint2 row-quad layout, 4 rows/wave/iter ---------
// lane l: row group rg=l>>4 (4 rows concurrent), feature quad cq=l&15.
__global__ __launch_bounds__(512) void k_colsum(const unsigned short* __restrict__ h3,
                                                float* __restrict__ colsum) {
    int t = threadIdx.x;
    int lane = t & 63;
    int rg = lane >> 4, cq = lane & 15;
    int wid = (blockIdx.x * 512 + t) >> 6;
    int nw = (gridDim.x * 512) >> 6;
    float a0 = 0, a1 = 0, a2 = 0, a3 = 0;
    for (int r = wid * 4 + rg; r < NN; r += nw * 4) {
        uint2 v = *(const uint2*)(h3 + ((size_t)r << 6) + cq * 4);
        a0 += bfu((unsigned short)(v.x & 0xFFFF));
        a1 += bfu((unsigned short)(v.x >> 16));
        a2 += bfu((unsigned short)(v.y & 0xFFFF));
        a3 += bfu((unsigned short)(v.y >> 16));
    }
    a0 += __shfl_xor(a0, 16, 64); a0 += __shfl_xor(a0, 32, 64);
    a1 += __shfl_xor(a1, 16, 64); a1 += __shfl_xor(a1, 32, 64);
    a2 += __shfl_xor(a2, 16, 64); a2 += __shfl_xor(a2, 32, 64);
    a3 += __shfl_xor(a3, 16, 64); a3 += __shfl_xor(a3, 32, 64);
    __shared__ float part[8][64];
    int w = t >> 6;
    if (rg == 0) {
        part[w][cq * 4 + 0] = a0;
        part[w][cq * 4 + 1] = a1;
        part[w][cq * 4 + 2] = a2;
        part[w][cq * 4 + 3] = a3;
    }
    __syncthreads();
    if (t < 64) {
        float s = 0;
#pragma unroll
        for (int i = 0; i < 8; i++) s += part[i][t];
        atomicAdd(&colsum[t], s);
    }
}

__global__ void k_ctx(const float* __restrict__ colsum, const float* __restrict__ Wa,
                      float* __restrict__ ctx) {
    __shared__ float ms[64];
    int j = threadIdx.x;
    ms[j] = colsum[j] * (1.0f / NN);
    __syncthreads();
    float s = 0.0f;
#pragma unroll
    for (int k = 0; k < 64; k++) s += ms[k] * Wa[k * 64 + j];
    ctx[j] = tanhf(s);
}

__global__ __launch_bounds__(512) void k_pool(const unsigned short* __restrict__ h3,
                                              const float* __restrict__ ctx,
                                              float* __restrict__ pooled) {
    int t = threadIdx.x;
    int lane = t & 63;
    int rg = lane >> 4, cq = lane & 15;
    int wid = (blockIdx.x * 512 + t) >> 6;
    int nw = (gridDim.x * 512) >> 6;
    float c0 = ctx[cq * 4 + 0], c1 = ctx[cq * 4 + 1];
    float c2 = ctx[cq * 4 + 2], c3 = ctx[cq * 4 + 3];
    float q0 = 0, q1 = 0, q2 = 0, q3 = 0;
    for (int r = wid * 4 + rg; r < NN; r += nw * 4) {
        uint2 v = *(const uint2*)(h3 + ((size_t)r << 6) + cq * 4);
        float x0 = bfu((unsigned short)(v.x & 0xFFFF));
        float x1 = bfu((unsigned short)(v.x >> 16));
        float x2 = bfu((unsigned short)(v.y & 0xFFFF));
        float x3 = bfu((unsigned short)(v.y >> 16));
        float p = x0 * c0 + x1 * c1 + x2 * c2 + x3 * c3;
        p += __shfl_xor(p, 1, 64);
        p += __shfl_xor(p, 2, 64);
        p += __shfl_xor(p, 4, 64);
        p += __shfl_xor(p, 8, 64);
        float sc = 1.0f / (1.0f + expf(-p));
        q0 += sc * x0; q1 += sc * x1; q2 += sc * x2; q3 += sc * x3;
    }
    q0 += __shfl_xor(q0, 16, 64); q0 += __shfl_xor(q0, 32, 64);
    q1 += __shfl_xor(q1, 16, 64); q1 += __shfl_xor(q1, 32, 64);
    q2 += __shfl_xor(q2, 16, 64); q2 += __shfl_xor(q2, 32, 64);
    q3 += __shfl_xor(q3, 16, 64); q3 += __shfl_xor(q3, 32, 64);
    __shared__ float part[8][64];
    int w = t >> 6;
    if (rg == 0) {
        part[w][cq * 4 + 0] = q0;
        part[w][cq * 4 + 1] = q1;
        part[w][cq * 4 + 2] = q2;
        part[w][cq * 4 + 3] = q3;
    }
    __syncthreads();
    if (t < 64) {
        float s = 0;
#pragma unroll
        for (int i = 0; i < 8; i++) s += part[i][t];
        atomicAdd(&pooled[t], s);
    }
}

// ---------------- final output write (4 elems/thread) ----------------
__global__ void k_out(const unsigned short* __restrict__ h3, const float* __restrict__ pooled,
                      void* __restrict__ out, const int* __restrict__ flags) {
    int q = blockIdx.x * blockDim.x + threadIdx.x;   // quad index; 6400064/4 = 1600016
    if (q >= 1600016) return;
    long long i0 = (long long)q * 4;
    float v[4];
#pragma unroll
    for (int k = 0; k < 4; k++) {
        long long i = i0 + k;
        v[k] = (i < 6400000LL) ? bfu(h3[i]) : pooled[i - 6400000LL];
    }
    if (flags[0]) {
        *(float4*)((float*)out + i0) = make_float4(v[0], v[1], v[2], v[3]);
    } else {
        unsigned lo = (unsigned)__bfloat16_as_ushort(__float2bfloat16(v[0])) |
                      ((unsigned)__bfloat16_as_ushort(__float2bfloat16(v[1])) << 16);
        unsigned hi = (unsigned)__bfloat16_as_ushort(__float2bfloat16(v[2])) |
                      ((unsigned)__bfloat16_as_ushort(__float2bfloat16(v[3])) << 16);
        *(uint2*)((unsigned short*)out + i0) = make_uint2(lo, hi);
    }
}

// ---------------- workspace layout (~21.5 MB) ----------------
static constexpr size_t AL(size_t x) { return (x + 255) & ~size_t(255); }
static constexpr size_t OFF_FLAGS  = 0;
static constexpr size_t OFF_RAW    = OFF_FLAGS + 256;
static constexpr size_t OFF_GHIST  = OFF_RAW + 256;
static constexpr size_t OFF_OFFM   = OFF_GHIST + AL((size_t)NBLK * NB2 * 4);
static constexpr size_t OFF_CBASE  = OFF_OFFM + AL((size_t)NBLK * NB2 * 4);
static constexpr size_t OFF_ROWPTR = OFF_CBASE + AL((NB2 + 1) * 4);
static constexpr size_t OFF_CSR    = OFF_ROWPTR + AL((NN + 1) * 4);
static constexpr size_t OFF_DIS    = OFF_CSR + AL((size_t)NE * 4);
static constexpr size_t OFF_P      = OFF_DIS + AL(NN * 4);     // NR*128 fp8; also scatter scratch; also bf16 h3
static constexpr size_t OFF_W1B    = OFF_P + AL((size_t)NR * 128);
static constexpr size_t OFF_W2B    = OFF_W1B + AL(16384 * 2);
static constexpr size_t OFF_W3B    = OFF_W2B + AL(16384 * 2);
static constexpr size_t OFF_B1F    = OFF_W3B + AL(8192 * 2);
static constexpr size_t OFF_B2F    = OFF_B1F + AL(128 * 4);
static constexpr size_t OFF_B3F    = OFF_B2F + AL(128 * 4);
static constexpr size_t OFF_WAF    = OFF_B3F + AL(64 * 4);
static constexpr size_t OFF_COLSUM = OFF_WAF + AL(4096 * 4);
static constexpr size_t OFF_POOLED = OFF_COLSUM + AL(64 * 4);
static constexpr size_t OFF_CTX    = OFF_POOLED + AL(64 * 4);

extern "C" void kernel_launch(void* const* d_in, const int* in_sizes, int n_in,
                              void* d_out, int out_size, void* d_ws, size_t ws_size,
                              hipStream_t stream) {
    const int* ei = (const int*)d_in[0];
    const void* x  = d_in[1];
    const void* W1 = d_in[2];
    const void* b1 = d_in[3];
    const void* W2 = d_in[4];
    const void* b2 = d_in[5];
    const void* W3 = d_in[6];
    const void* b3 = d_in[7];
    const void* Wa = d_in[8];

    char* ws = (char*)d_ws;
    int*   flags  = (int*)(ws + OFF_FLAGS);
    int*   raw    = (int*)(ws + OFF_RAW);
    int*   ghist  = (int*)(ws + OFF_GHIST);
    int*   offm   = (int*)(ws + OFF_OFFM);
    int*   cbase  = (int*)(ws + OFF_CBASE);
    int*   rowptr = (int*)(ws + OFF_ROWPTR);
    int*   csr    = (int*)(ws + OFF_CSR);
    float* dis    = (float*)(ws + OFF_DIS);
    unsigned char*  P    = (unsigned char*)(ws + OFF_P);
    int*            scrA = (int*)(ws + OFF_P);
    unsigned short* Hb   = (unsigned short*)(ws + OFF_P);
    unsigned short* W1b = (unsigned short*)(ws + OFF_W1B);
    unsigned short* W2b = (unsigned short*)(ws + OFF_W2B);
    unsigned short* W3b = (unsigned short*)(ws + OFF_W3B);
    float* b1f    = (float*)(ws + OFF_B1F);
    float* b2f    = (float*)(ws + OFF_B2F);
    float* b3f    = (float*)(ws + OFF_B3F);
    float* Waf    = (float*)(ws + OFF_WAF);
    float* colsum = (float*)(ws + OFF_COLSUM);
    float* pooled = (float*)(ws + OFF_POOLED);
    float* ctx    = (float*)(ws + OFF_CTX);

    unsigned char* Q = (unsigned char*)d_out;   // d_out doubles as T-scratch (12.8 MB)

    hipMemsetAsync(raw, 0, 256, stream);
    hipMemsetAsync(colsum, 0, 64 * 4, stream);
    hipMemsetAsync(pooled, 0, 64 * 4, stream);

    k_probe1<<<256, 256, 0, stream>>>((const unsigned short*)x, ei, raw);
    k_probe2<<<1, 64, 0, stream>>>(raw, flags);
    cvt_params<<<64, 256, 0, stream>>>(W1, b1, W2, b2, W3, b3, Wa,
                                       W1b, W2b, W3b, b1f, b2f, b3f, Waf, flags);

    // atomic-free CSR build
    k_hist<<<NBLK, 256, 0, stream>>>(ei, ghist, flags);
    k_off<<<1, 256, 0, stream>>>(ghist, cbase, offm, rowptr);
    k_scatter<<<NBLK, 256, 0, stream>>>(ei, offm, scrA, flags);
    k_build<<<NB2, 256, 0, stream>>>(scrA, cbase, rowptr, dis, csr);

    // x -> fp8 P (overwrites scatter scratch)
    k_cvtx<<<(NN * 128 / 4 + 255) / 256, 256, 0, stream>>>(x, P, flags);

    // L1: T = P@W1 (Q, MFMA) ; P = relu(Anorm@T + b1)
    k_xf_mfma<8><<<NR / 64, 256, 0, stream>>>(P, W1b, Q);
    k_agg128<true><<<NN / 4, 256, 0, stream>>>(Q, rowptr, csr, dis, b1f, P);
    // L2
    k_xf_mfma<8><<<NR / 64, 256, 0, stream>>>(P, W2b, Q);
    k_agg128<true><<<NN / 4, 256, 0, stream>>>(Q, rowptr, csr, dis, b2f, P);
    // L3: T3 = P@W3 (Q, 64 cols) ; Hb = Anorm@T3 + b3 (bf16, overwrites P)
    k_xf_mfma<4><<<NR / 64, 256, 0, stream>>>(P, W3b, Q);
    k_agg64<<<NN / 4, 256, 0, stream>>>(Q, rowptr, csr, dis, b3f, Hb);

    // attention pooling (v2)
    k_colsum<<<256, 512, 0, stream>>>(Hb, colsum);
    k_ctx<<<1, 64, 0, stream>>>(colsum, Waf, ctx);
    k_pool<<<256, 512, 0, stream>>>(Hb, ctx, pooled);

    // final output
    k_out<<<(1600016 + 255) / 256, 256, 0, stream>>>(Hb, pooled, d_out, flags);
}